// Round 4
// baseline (511.289 us; speedup 1.0000x reference)
//
#include <hip/hip_runtime.h>

typedef __bf16 bf16;
typedef __attribute__((ext_vector_type(4))) __bf16 bf16x4;
typedef __attribute__((ext_vector_type(8))) __bf16 bf16x8;
typedef __attribute__((ext_vector_type(4))) float f32x4;

#define MFMA_BF16(A_, B_, C_) __builtin_amdgcn_mfma_f32_16x16x32_bf16(A_, B_, C_, 0, 0, 0)

// Problem dims
#define BB    32
#define SEQ   577
#define CH    768
#define NH    12
#define DHD   64
#define MROWS (BB * SEQ)   // 18464
#define NQKV  2304
#define SEQP  584          // V^T row stride (73*8)
// q scale folded with log2(e): softmax computed in base-2 domain
#define QSCALE 0.1803368801111204f

// ---- async global->LDS 16B (wave-uniform LDS base + lane*16, per guide §5) ----
__device__ __forceinline__ void async_ld16(const bf16* g, bf16* l) {
  __builtin_amdgcn_global_load_lds(
      (const __attribute__((address_space(1))) void*)g,
      (__attribute__((address_space(3))) void*)l, 16, 0, 0);
}

// ---- fp32 -> bf16 convert ----
__global__ __launch_bounds__(256) void cvt_bf16(const float* __restrict__ src,
                                                bf16* __restrict__ dst, int n) {
  int idx = (blockIdx.x * 256 + threadIdx.x) * 4;
  if (idx >= n) return;
  float4 v = *(const float4*)(src + idx);
  bf16x4 o = {(bf16)v.x, (bf16)v.y, (bf16)v.z, (bf16)v.w};
  *(bf16x4*)(dst + idx) = o;
}

// ---- zero the 7-element pad of each V^T row (j in [577,584)) so attention's
// direct-global V reads at jc=576 see finite values regardless of workspace state.
__global__ __launch_bounds__(256) void pad_v(bf16* __restrict__ vt) {
  int r = blockIdx.x * 256 + threadIdx.x;
  if (r < BB * NH * DHD) {
    bf16* p = vt + (size_t)r * SEQP + SEQ;
#pragma unroll
    for (int i = 0; i < 7; ++i) p[i] = (bf16)0.f;
  }
}

// ---- 128x128x(K=768) bf16 MFMA GEMM, B given as rows of W [n][k] (x @ W^T) ----
// R0-proven structure (best measured: 145us qkv). Double-buffered single-barrier
// K-loop: loads for step k+1 issued right after the barrier, drained by the NEXT
// barrier -> each drain has a full compute phase of slack.
// Grid: x = n-tiles (fast -> A m-tile reused across consecutive blocks), y = m-tiles.
// EPI 0: qkv epilogue: q -> qrm [M,768] (scaled), k -> krm [M,768], v -> vt [B,H,64,SEQP]
// EPI 1: proj epilogue: bias, fp32 out [M,768]
template <int EPI>
__global__ __launch_bounds__(256, 2)
void gemm_bt(const bf16* __restrict__ A, const bf16* __restrict__ W,
             const float* __restrict__ bias,
             bf16* __restrict__ qrm, bf16* __restrict__ krm, bf16* __restrict__ vt,
             float* __restrict__ out) {
  __shared__ bf16 As[2][128 * 32];
  __shared__ bf16 Bs[2][128 * 32];
  const int tid = threadIdx.x, lane = tid & 63, wid = tid >> 6;
  const int quad = lane >> 4, r15 = lane & 15;
  const int m0 = blockIdx.y * 128, n0 = blockIdx.x * 128;
  const int waveM = wid & 1, waveN = wid >> 1;

  // staging: 512 16B chunks per tile; XOR chunk swizzle -> fragment ds_read_b128 2-way (free)
  const bf16* aSrc[2];
  const bf16* bSrc[2];
  for (int c = 0; c < 2; ++c) {
    int q = wid * 128 + c * 64 + lane;
    int row = q >> 2;
    int sw = (row ^ (row >> 2)) & 3;
    int kc = (q & 3) ^ sw;
    aSrc[c] = A + (size_t)(m0 + row) * CH + kc * 8;
    bSrc[c] = W + (size_t)(n0 + row) * CH + kc * 8;
  }

  f32x4 acc[4][4];
#pragma unroll
  for (int i = 0; i < 4; ++i)
#pragma unroll
    for (int j = 0; j < 4; ++j) acc[i][j] = (f32x4){0.f, 0.f, 0.f, 0.f};

#define GSTAGE(K0, BUF)                                                   \
  {                                                                       \
    _Pragma("unroll") for (int c = 0; c < 2; ++c) {                       \
      async_ld16(aSrc[c] + (K0), &As[BUF][(wid * 128 + c * 64) * 8]);     \
      async_ld16(bSrc[c] + (K0), &Bs[BUF][(wid * 128 + c * 64) * 8]);     \
    }                                                                     \
  }

#define GCOMPUTE(BUF)                                                     \
  {                                                                       \
    bf16x8 af[4], bfr[4];                                                 \
    _Pragma("unroll") for (int s = 0; s < 4; ++s) {                       \
      int rowA = waveM * 64 + s * 16 + r15;                               \
      int ca = quad ^ ((rowA ^ (rowA >> 2)) & 3);                         \
      af[s] = *(const bf16x8*)(&As[BUF][rowA * 32 + ca * 8]);             \
      int rowB = waveN * 64 + s * 16 + r15;                               \
      int cb = quad ^ ((rowB ^ (rowB >> 2)) & 3);                         \
      bfr[s] = *(const bf16x8*)(&Bs[BUF][rowB * 32 + cb * 8]);            \
    }                                                                     \
    _Pragma("unroll") for (int sm = 0; sm < 4; ++sm)                      \
      _Pragma("unroll") for (int sn = 0; sn < 4; ++sn)                    \
        acc[sm][sn] = MFMA_BF16(af[sm], bfr[sn], acc[sm][sn]);            \
  }

  GSTAGE(0, 0);
  for (int k0 = 0; k0 < CH; k0 += 64) {
    __syncthreads();                       // drains buf0 loads (issued prev iter / prologue)
    GSTAGE(k0 + 32, 1);                    // overlaps compute on buf0
    GCOMPUTE(0);
    __syncthreads();                       // drains buf1 loads; all waves done with buf0
    if (k0 + 64 < CH) GSTAGE(k0 + 64, 0);  // overlaps compute on buf1
    GCOMPUTE(1);
  }

  // epilogue: C/D layout row=(lane>>4)*4+reg, col=lane&15 (verified m89/m91)
  if (EPI == 0) {
    int t = (n0 >= 1536) ? 2 : (n0 >= 768 ? 1 : 0);  // 128-tiles never straddle 768
#pragma unroll
    for (int sn = 0; sn < 4; ++sn) {
      int gn = n0 + waveN * 64 + sn * 16 + r15;
      float bv = bias[gn];
      int col = gn - t * CH;  // [0,768)
      int h = col >> 6, d = col & 63;
#pragma unroll
      for (int sm = 0; sm < 4; ++sm) {
        int gmBase = m0 + waveM * 64 + sm * 16 + quad * 4;
#pragma unroll
        for (int r = 0; r < 4; ++r) {
          int gm = gmBase + r;
          if (gm < MROWS) {
            float v = acc[sm][sn][r] + bv;
            if (t == 0) {
              qrm[(size_t)gm * CH + col] = (bf16)(v * QSCALE);
            } else if (t == 1) {
              krm[(size_t)gm * CH + col] = (bf16)v;
            } else {
              int b_ = gm / SEQ;
              int n_ = gm - b_ * SEQ;
              vt[((size_t)(b_ * NH + h) * DHD + d) * SEQP + n_] = (bf16)v;
            }
          }
        }
      }
    }
  } else {
#pragma unroll
    for (int sn = 0; sn < 4; ++sn) {
      int gn = n0 + waveN * 64 + sn * 16 + r15;
      float bv = bias[gn];
#pragma unroll
      for (int sm = 0; sm < 4; ++sm) {
        int gmBase = m0 + waveM * 64 + sm * 16 + quad * 4;
#pragma unroll
        for (int r = 0; r < 4; ++r) {
          int gm = gmBase + r;
          if (gm < MROWS) out[(size_t)gm * CH + gn] = acc[sm][sn][r] + bv;
        }
      }
    }
  }
}

// ---- flash attention, NO-MAX softmax, R4: ZERO LDS staging, ZERO barriers ----
// K/V per (b,h) = 147KB -> L2-resident, reused by 10 q-blocks. Staging it in LDS
// was pure overhead (guide common-mistake #7 / m169): 38 LDS ops + 3 barriers per
// wave-tile. Now MFMA B-fragments for QK^T and PV are loaded DIRECTLY from global:
// each fragment instr = 16 rows x 64B contiguous (quads cover 4x16B per row) -> L2.
// LDS holds only the per-wave-PRIVATE P round-trip (C-layout -> A-layout), so the
// j-loop has NO cross-wave synchronization: 24 waves/CU run free, TLP hides L2 lat.
// OOB handling: K rows clamped to 576 (valid, masked later). V chunk jc<=576 always
// (16B-aligned); jc=576 reads the 7-elem row pad, zeroed by pad_v, and those k-slots
// have P=0 (masked) -> contribution 0. jc>576 chunks clamp to 576; their P=0 too.
__global__ __launch_bounds__(256, 6)
void attn_kernel(const bf16* __restrict__ qrm, const bf16* __restrict__ krm,
                 const bf16* __restrict__ vt, bf16* __restrict__ ob) {
  __shared__ bf16 Ps[4][16 * 72];  // per-wave private P buffer (pad 72)
  const int tid = threadIdx.x, lane = tid & 63, wid = tid >> 6;
  const int quad = lane >> 4, r15 = lane & 15;
  const int qt = blockIdx.x, bh = blockIdx.y;
  const int b_ = bh / NH, h = bh - b_ * NH;
  const bf16* vtb = vt + (size_t)bh * DHD * SEQP;
  const bf16* kb = krm + (size_t)b_ * SEQ * CH + h * DHD;  // + row*CH + quad*8

  // Q fragments resident (A layout: m=lane&15, k=quad*8+j); q pre-scaled by 0.125*log2e
  int qrow = qt * 64 + wid * 16 + r15;
  if (qrow > SEQ - 1) qrow = SEQ - 1;
  const bf16* qp = qrm + (size_t)(b_ * SEQ + qrow) * CH + h * DHD + quad * 8;
  bf16x8 qf0 = *(const bf16x8*)qp;
  bf16x8 qf1 = *(const bf16x8*)(qp + 32);

  f32x4 oacc[4];
#pragma unroll
  for (int i = 0; i < 4; ++i) oacc[i] = (f32x4){0.f, 0.f, 0.f, 0.f};
  float lrow[4] = {0.f, 0.f, 0.f, 0.f};  // per-LANE partial row sums

  bf16* Pw = Ps[wid];

  for (int j0 = 0; j0 < SEQ; j0 += 64) {
    // S = Q K^T (16 q-rows x 64 cols per wave), base-2 domain; K direct from L2
    f32x4 s[4];
#pragma unroll
    for (int sj = 0; sj < 4; ++sj) {
      int jr = j0 + sj * 16 + r15;
      if (jr > SEQ - 1) jr = SEQ - 1;
      const bf16* kp = kb + (size_t)jr * CH + quad * 8;
      bf16x8 kf0 = *(const bf16x8*)kp;
      bf16x8 kf1 = *(const bf16x8*)(kp + 32);
      f32x4 z = (f32x4){0.f, 0.f, 0.f, 0.f};
      s[sj] = MFMA_BF16(qf0, kf0, z);
      s[sj] = MFMA_BF16(qf1, kf1, s[sj]);
    }
#pragma unroll
    for (int sj = 0; sj < 4; ++sj)
      if (j0 + sj * 16 + r15 > SEQ - 1) s[sj] = (f32x4){-1e30f, -1e30f, -1e30f, -1e30f};

    // P = exp2(S) unshifted; accumulate per-lane row sums (no shuffles, no rescale)
#pragma unroll
    for (int sj = 0; sj < 4; ++sj)
#pragma unroll
      for (int r = 0; r < 4; ++r) {
        float e = __builtin_amdgcn_exp2f(s[sj][r]);
        s[sj][r] = e;
        lrow[r] += e;
      }

    // P: C/D layout -> LDS (wave-private) -> A layout. Same-wave RAW only.
#pragma unroll
    for (int sj = 0; sj < 4; ++sj)
#pragma unroll
      for (int r = 0; r < 4; ++r)
        Pw[(quad * 4 + r) * 72 + sj * 16 + r15] = (bf16)s[sj][r];
    asm volatile("s_waitcnt lgkmcnt(0)" ::: "memory");

    // O += P V ; V^T fragments direct from L2
#pragma unroll
    for (int kc = 0; kc < 2; ++kc) {
      bf16x8 pf = *(const bf16x8*)(Pw + r15 * 72 + kc * 32 + quad * 8);
      int jc = j0 + kc * 32 + quad * 8;
      if (jc > SEQ - 1) jc = SEQ - 1 - 7;  // 576: 16B-aligned; pad zeroed; P=0 slots
#pragma unroll
      for (int sd = 0; sd < 4; ++sd) {
        bf16x8 vf = *(const bf16x8*)(vtb + (size_t)(sd * 16 + r15) * SEQP + jc);
        oacc[sd] = MFMA_BF16(pf, vf, oacc[sd]);
      }
    }
  }

  // ONE shuffle reduction: row sum over the 16 lanes of each quad-group
#pragma unroll
  for (int r = 0; r < 4; ++r) {
    float rs = lrow[r];
    rs += __shfl_xor(rs, 1);
    rs += __shfl_xor(rs, 2);
    rs += __shfl_xor(rs, 4);
    rs += __shfl_xor(rs, 8);
    lrow[r] = rs;
  }

  // write O -> attn_out [b*577+n][h*64+d] bf16 row-major
#pragma unroll
  for (int r = 0; r < 4; ++r) {
    int orow = qt * 64 + wid * 16 + quad * 4 + r;
    if (orow < SEQ) {
      float inv = 1.0f / lrow[r];
      size_t rowoff = ((size_t)(b_ * SEQ + orow)) * CH + h * DHD;
#pragma unroll
      for (int sd = 0; sd < 4; ++sd)
        ob[rowoff + sd * 16 + r15] = (bf16)(oacc[sd][r] * inv);
    }
  }
}

extern "C" void kernel_launch(void* const* d_in, const int* in_sizes, int n_in,
                              void* d_out, int out_size, void* d_ws, size_t ws_size,
                              hipStream_t stream) {
  const float* x      = (const float*)d_in[0];
  const float* qkv_w  = (const float*)d_in[1];
  const float* qkv_b  = (const float*)d_in[2];
  const float* proj_w = (const float*)d_in[3];
  const float* proj_b = (const float*)d_in[4];
  float* out = (float*)d_out;

  char* w = (char*)d_ws;
  // workspace layout (bytes), total 117,325,824:
  bf16* xb  = (bf16*)(w);               // [18464,768] x_bf16, reused as attn_out
  bf16* wqp = (bf16*)(w + 28360704);    // qkv_w bf16; later aliased by proj_w bf16
  bf16* qrm = (bf16*)(w + 31899648);    // [18464,768] scaled Q
  bf16* krm = (bf16*)(w + 60260352);    // [18464,768] K
  bf16* vtb = (bf16*)(w + 88621056);    // [32,12,64,584] V^T
  // GEMM m-tail (rows 18464..18559) reads spill into the wqp region: finite, discarded.

  cvt_bf16<<<(MROWS * CH / 4 + 255) / 256, 256, 0, stream>>>(x, xb, MROWS * CH);
  cvt_bf16<<<(NQKV * CH / 4 + 255) / 256, 256, 0, stream>>>(qkv_w, wqp, NQKV * CH);
  pad_v<<<(BB * NH * DHD + 255) / 256, 256, 0, stream>>>(vtb);

  gemm_bt<0><<<dim3(NQKV / 128, 145), 256, 0, stream>>>(
      xb, wqp, qkv_b, qrm, krm, vtb, nullptr);

  attn_kernel<<<dim3(10, BB * NH), 256, 0, stream>>>(qrm, krm, vtb, xb);

  // proj weights convert AFTER attention (stream-ordered) so it can alias wqp
  cvt_bf16<<<(CH * CH / 4 + 255) / 256, 256, 0, stream>>>(proj_w, wqp, CH * CH);

  gemm_bt<1><<<dim3(CH / 128, 145), 256, 0, stream>>>(
      xb, wqp, proj_b, nullptr, nullptr, nullptr, out);
}

// Round 5
// 376.689 us; speedup vs baseline: 1.3573x; 1.3573x over previous
//
#include <hip/hip_runtime.h>

typedef __bf16 bf16;
typedef __attribute__((ext_vector_type(4))) __bf16 bf16x4;
typedef __attribute__((ext_vector_type(8))) __bf16 bf16x8;
typedef __attribute__((ext_vector_type(4))) float f32x4;

#define MFMA_BF16(A_, B_, C_) __builtin_amdgcn_mfma_f32_16x16x32_bf16(A_, B_, C_, 0, 0, 0)

// Problem dims
#define BB    32
#define SEQ   577
#define CH    768
#define NH    12
#define DHD   64
#define MROWS (BB * SEQ)   // 18464
#define NQKV  2304
#define SEQP  584          // V^T row stride (73*8)
// q scale folded with log2(e): softmax computed in base-2 domain
#define QSCALE 0.1803368801111204f

#define NSTEP 24           // K-steps of 32 for the 256^2 proj GEMM (768 = 24*32)

// ---- async global->LDS 16B (wave-uniform LDS base + lane*16, per guide §5) ----
__device__ __forceinline__ void async_ld16(const bf16* g, bf16* l) {
  __builtin_amdgcn_global_load_lds(
      (const __attribute__((address_space(1))) void*)g,
      (__attribute__((address_space(3))) void*)l, 16, 0, 0);
}

// ---- fp32 -> bf16 convert ----
__global__ __launch_bounds__(256) void cvt_bf16(const float* __restrict__ src,
                                                bf16* __restrict__ dst, int n) {
  int idx = (blockIdx.x * 256 + threadIdx.x) * 4;
  if (idx >= n) return;
  float4 v = *(const float4*)(src + idx);
  bf16x4 o = {(bf16)v.x, (bf16)v.y, (bf16)v.z, (bf16)v.w};
  *(bf16x4*)(dst + idx) = o;
}

// ---- zero the 7-element pad of each V^T row (j in [577,584)) so attention's
// staged V reads at jst=576 see finite values regardless of workspace state.
__global__ __launch_bounds__(256) void pad_v(bf16* __restrict__ vt) {
  int r = blockIdx.x * 256 + threadIdx.x;
  if (r < BB * NH * DHD) {
    bf16* p = vt + (size_t)r * SEQP + SEQ;
#pragma unroll
    for (int i = 0; i < 7; ++i) p[i] = (bf16)0.f;
  }
}

// ---- 128x128x(K=768) bf16 MFMA GEMM (qkv), R0-proven structure (146us) ----
// Double-buffered single-barrier K-loop: loads for step k+1 issued right after the
// barrier, drained by the NEXT barrier -> each drain has a full compute phase of slack.
// Grid: x = n-tiles (fast -> A m-tile reused across consecutive blocks), y = m-tiles.
// qkv epilogue: q -> qrm [M,768] (scaled), k -> krm [M,768], v -> vt [B,H,64,SEQP]
__global__ __launch_bounds__(256, 2)
void gemm_qkv(const bf16* __restrict__ A, const bf16* __restrict__ W,
              const float* __restrict__ bias,
              bf16* __restrict__ qrm, bf16* __restrict__ krm, bf16* __restrict__ vt) {
  __shared__ bf16 As[2][128 * 32];
  __shared__ bf16 Bs[2][128 * 32];
  const int tid = threadIdx.x, lane = tid & 63, wid = tid >> 6;
  const int quad = lane >> 4, r15 = lane & 15;
  const int m0 = blockIdx.y * 128, n0 = blockIdx.x * 128;
  const int waveM = wid & 1, waveN = wid >> 1;

  // staging: 512 16B chunks per tile; XOR chunk swizzle -> fragment ds_read_b128 2-way (free)
  const bf16* aSrc[2];
  const bf16* bSrc[2];
  for (int c = 0; c < 2; ++c) {
    int q = wid * 128 + c * 64 + lane;
    int row = q >> 2;
    int sw = (row ^ (row >> 2)) & 3;
    int kc = (q & 3) ^ sw;
    aSrc[c] = A + (size_t)(m0 + row) * CH + kc * 8;
    bSrc[c] = W + (size_t)(n0 + row) * CH + kc * 8;
  }

  f32x4 acc[4][4];
#pragma unroll
  for (int i = 0; i < 4; ++i)
#pragma unroll
    for (int j = 0; j < 4; ++j) acc[i][j] = (f32x4){0.f, 0.f, 0.f, 0.f};

#define GSTAGE(K0, BUF)                                                   \
  {                                                                       \
    _Pragma("unroll") for (int c = 0; c < 2; ++c) {                       \
      async_ld16(aSrc[c] + (K0), &As[BUF][(wid * 128 + c * 64) * 8]);     \
      async_ld16(bSrc[c] + (K0), &Bs[BUF][(wid * 128 + c * 64) * 8]);     \
    }                                                                     \
  }

#define GCOMPUTE(BUF)                                                     \
  {                                                                       \
    bf16x8 af[4], bfr[4];                                                 \
    _Pragma("unroll") for (int s = 0; s < 4; ++s) {                       \
      int rowA = waveM * 64 + s * 16 + r15;                               \
      int ca = quad ^ ((rowA ^ (rowA >> 2)) & 3);                         \
      af[s] = *(const bf16x8*)(&As[BUF][rowA * 32 + ca * 8]);             \
      int rowB = waveN * 64 + s * 16 + r15;                               \
      int cb = quad ^ ((rowB ^ (rowB >> 2)) & 3);                         \
      bfr[s] = *(const bf16x8*)(&Bs[BUF][rowB * 32 + cb * 8]);            \
    }                                                                     \
    _Pragma("unroll") for (int sm = 0; sm < 4; ++sm)                      \
      _Pragma("unroll") for (int sn = 0; sn < 4; ++sn)                    \
        acc[sm][sn] = MFMA_BF16(af[sm], bfr[sn], acc[sm][sn]);            \
  }

  GSTAGE(0, 0);
  for (int k0 = 0; k0 < CH; k0 += 64) {
    __syncthreads();                       // drains buf0 loads (issued prev iter / prologue)
    GSTAGE(k0 + 32, 1);                    // overlaps compute on buf0
    GCOMPUTE(0);
    __syncthreads();                       // drains buf1 loads; all waves done with buf0
    if (k0 + 64 < CH) GSTAGE(k0 + 64, 0);  // overlaps compute on buf1
    GCOMPUTE(1);
  }

  // epilogue: C/D layout row=(lane>>4)*4+reg, col=lane&15 (verified m89/m91)
  int t = (n0 >= 1536) ? 2 : (n0 >= 768 ? 1 : 0);  // 128-tiles never straddle 768
#pragma unroll
  for (int sn = 0; sn < 4; ++sn) {
    int gn = n0 + waveN * 64 + sn * 16 + r15;
    float bv = bias[gn];
    int col = gn - t * CH;  // [0,768)
    int h = col >> 6, d = col & 63;
#pragma unroll
    for (int sm = 0; sm < 4; ++sm) {
      int gmBase = m0 + waveM * 64 + sm * 16 + quad * 4;
#pragma unroll
      for (int r = 0; r < 4; ++r) {
        int gm = gmBase + r;
        if (gm < MROWS) {
          float v = acc[sm][sn][r] + bv;
          if (t == 0) {
            qrm[(size_t)gm * CH + col] = (bf16)(v * QSCALE);
          } else if (t == 1) {
            krm[(size_t)gm * CH + col] = (bf16)v;
          } else {
            int b_ = gm / SEQ;
            int n_ = gm - b_ * SEQ;
            vt[((size_t)(b_ * NH + h) * DHD + d) * SEQP + n_] = (bf16)v;
          }
        }
      }
    }
  }
}
#undef GSTAGE
#undef GCOMPUTE

// ---- 256x256x(K=768) proj GEMM, R3-proven (proj in a single 219-block round,
// ~15us faster than the 128^2 proj). Counted-vmcnt pipeline, 4 LDS buffers,
// prefetch distance 2, one raw s_barrier per 32-K step. ----
__global__ __launch_bounds__(512, 2)
void gemm_proj(const bf16* __restrict__ A, const bf16* __restrict__ W,
               const float* __restrict__ bias, float* __restrict__ out) {
  __shared__ bf16 As[4][256 * 32];  // [buf][row*32 + chunk2*8], 16 KiB each
  __shared__ bf16 Bs[4][256 * 32];
  const int tid = threadIdx.x, lane = tid & 63, wid = tid >> 6;
  const int quad = lane >> 4, r15 = lane & 15;

  const int nbx = (int)gridDim.x;
  const int nwg = nbx * (int)gridDim.y;
  int bid = (int)blockIdx.y * nbx + (int)blockIdx.x;
  int q8 = nwg >> 3, r8 = nwg & 7;
  int xcd = bid & 7, sub = bid >> 3;
  int wg = (xcd < r8 ? xcd * (q8 + 1) : r8 * (q8 + 1) + (xcd - r8) * q8) + sub;
  const int m0 = (wg / nbx) * 256, n0 = (wg % nbx) * 256;

  const int rm = (wid >> 2) * 128;  // wave row base (2 waves in M)
  const int rn = (wid & 3) * 64;    // wave col base (4 waves in N)

  int aOff[2], bOff[2];
#pragma unroll
  for (int i = 0; i < 2; ++i) {
    int slot = i * 512 + tid;
    int row = slot >> 2, pc2 = slot & 3;
    int gc2 = pc2 ^ ((row ^ (row >> 2)) & 3);
    aOff[i] = (m0 + row) * CH + gc2 * 8;
    bOff[i] = (n0 + row) * CH + gc2 * 8;
  }

  f32x4 acc[8][4];
#pragma unroll
  for (int i = 0; i < 8; ++i)
#pragma unroll
    for (int j = 0; j < 4; ++j) acc[i][j] = (f32x4){0.f, 0.f, 0.f, 0.f};

#define ISSUE2(S)                                                              \
  {                                                                            \
    const int kb_ = (S) * 32;                                                  \
    const int bf_ = (S) & 3;                                                   \
    _Pragma("unroll") for (int i = 0; i < 2; ++i) {                            \
      async_ld16(A + aOff[i] + kb_, &As[bf_][(i * 512 + tid) * 8]);            \
      async_ld16(W + bOff[i] + kb_, &Bs[bf_][(i * 512 + tid) * 8]);            \
    }                                                                          \
  }

#define COMPUTE2(BF)                                                           \
  {                                                                            \
    bf16x8 bfr[4], afr[8];                                                     \
    _Pragma("unroll") for (int sn = 0; sn < 4; ++sn) {                         \
      int fr = rn + sn * 16 + r15;                                             \
      int pc2 = quad ^ ((fr ^ (fr >> 2)) & 3);                                 \
      bfr[sn] = *(const bf16x8*)(&Bs[BF][fr * 32 + pc2 * 8]);                  \
    }                                                                          \
    _Pragma("unroll") for (int sm = 0; sm < 8; ++sm) {                         \
      int fr = rm + sm * 16 + r15;                                             \
      int pc2 = quad ^ ((fr ^ (fr >> 2)) & 3);                                 \
      afr[sm] = *(const bf16x8*)(&As[BF][fr * 32 + pc2 * 8]);                  \
    }                                                                          \
    _Pragma("unroll") for (int sm = 0; sm < 8; ++sm)                           \
      _Pragma("unroll") for (int sn = 0; sn < 4; ++sn)                         \
        acc[sm][sn] = MFMA_BF16(afr[sm], bfr[sn], acc[sm][sn]);                \
  }

  ISSUE2(0);
  ISSUE2(1);
  for (int s = 0; s < NSTEP; ++s) {
    if (s < NSTEP - 2) {
      ISSUE2(s + 2);
      asm volatile("s_waitcnt vmcnt(8)" ::: "memory");
    } else if (s == NSTEP - 2) {
      asm volatile("s_waitcnt vmcnt(4)" ::: "memory");
    } else {
      asm volatile("s_waitcnt vmcnt(0)" ::: "memory");
    }
    __builtin_amdgcn_s_barrier();
    asm volatile("" ::: "memory");
    COMPUTE2(s & 3);
  }

  // epilogue: bias + fp32 out
#pragma unroll
  for (int sn = 0; sn < 4; ++sn) {
    int gn = n0 + rn + sn * 16 + r15;
    float bv = bias[gn];
#pragma unroll
    for (int sm = 0; sm < 8; ++sm) {
      int gmBase = m0 + rm + sm * 16 + quad * 4;
#pragma unroll
      for (int r = 0; r < 4; ++r) {
        int gm = gmBase + r;
        if (gm < MROWS) out[(size_t)gm * CH + gn] = acc[sm][sn][r] + bv;
      }
    }
  }
}
#undef ISSUE2
#undef COMPUTE2

// ---- flash attention, NO-MAX softmax (scores bounded; base-2 domain) ----
// R5: R0-proven LDS-staged structure, but each wave now owns 32 q-rows (two
// 16-row groups g=0,1) -> each staged K/V tile feeds 2x the MFMA work:
//   - staging instr + barriers amortized 2x (2 barriers per 128 q-rows vs 6)
//   - P gets its own wave-PRIVATE LDS buffer (no longer aliased on Ks), which
//     deletes the third barrier per tile entirely (no cross-wave P hazard).
// Blocks: 5 x 384 = 1920, LDS 27.6KB -> 5 blocks/CU.
__global__ __launch_bounds__(256, 5)
void attn_kernel(const bf16* __restrict__ qrm, const bf16* __restrict__ krm,
                 const bf16* __restrict__ vt, bf16* __restrict__ ob) {
  __shared__ bf16 Ks[64 * 72];      // K tile [j][d] pad 72
  __shared__ bf16 Vt[64 * 72];      // V^T tile [d][j] pad 72
  __shared__ bf16 Ps[4][16 * 72];   // per-wave private P buffer (pad 72)
  const int tid = threadIdx.x, lane = tid & 63, wid = tid >> 6;
  const int quad = lane >> 4, r15 = lane & 15;
  const int qt = blockIdx.x, bh = blockIdx.y;
  const int b_ = bh / NH, h = bh - b_ * NH;
  const bf16* vtb = vt + (size_t)bh * DHD * SEQP;

  // Q fragments resident for both row groups (A layout: m=lane&15, k=quad*8+j);
  // q pre-scaled by 0.125*log2e
  bf16x8 qf[2][2];
#pragma unroll
  for (int g = 0; g < 2; ++g) {
    int qrow = qt * 128 + wid * 32 + g * 16 + r15;
    if (qrow > SEQ - 1) qrow = SEQ - 1;
    const bf16* qp = qrm + (size_t)(b_ * SEQ + qrow) * CH + h * DHD + quad * 8;
    qf[g][0] = *(const bf16x8*)qp;
    qf[g][1] = *(const bf16x8*)(qp + 32);
  }

  f32x4 oacc[2][4];
#pragma unroll
  for (int g = 0; g < 2; ++g)
#pragma unroll
    for (int i = 0; i < 4; ++i) oacc[g][i] = (f32x4){0.f, 0.f, 0.f, 0.f};
  float lrow[2][4] = {{0.f, 0.f, 0.f, 0.f}, {0.f, 0.f, 0.f, 0.f}};

  bf16* Pw = Ps[wid];

  for (int j0 = 0; j0 < SEQ; j0 += 64) {
    __syncthreads();  // all waves done reading Ks/Vt of previous tile
    // stage K [64 j x 64 d] and V^T [64 d x 64 j]: 512 x 16B chunks each
#pragma unroll
    for (int c = 0; c < 2; ++c) {
      int sid = c * 256 + tid;           // [0,512)
      int row = sid >> 3, cc = sid & 7;  // row in [0,64), chunk in [0,8)
      int jr = j0 + row;
      if (jr > SEQ - 1) jr = SEQ - 1;
      *(bf16x8*)(Ks + row * 72 + cc * 8) =
          *(const bf16x8*)(krm + (size_t)(b_ * SEQ + jr) * CH + h * DHD + cc * 8);
      int jst = j0 + cc * 8;             // V^T chunk start; clamp keeps reads in-bounds,
      if (jst > SEQ - 1) jst = SEQ - 1;  // pad cols zeroed by pad_v; P=0 there anyway
      *(bf16x8*)(Vt + row * 72 + cc * 8) = *(const bf16x8*)(vtb + (size_t)row * SEQP + jst);
    }
    __syncthreads();

#pragma unroll
    for (int g = 0; g < 2; ++g) {
      // S = Q K^T (16 q-rows x 64 cols per wave-group), base-2 domain
      f32x4 s[4];
#pragma unroll
      for (int sj = 0; sj < 4; ++sj) {
        bf16x8 kf0 = *(const bf16x8*)(Ks + (sj * 16 + r15) * 72 + quad * 8);
        bf16x8 kf1 = *(const bf16x8*)(Ks + (sj * 16 + r15) * 72 + 32 + quad * 8);
        f32x4 z = (f32x4){0.f, 0.f, 0.f, 0.f};
        s[sj] = MFMA_BF16(qf[g][0], kf0, z);
        s[sj] = MFMA_BF16(qf[g][1], kf1, s[sj]);
      }
#pragma unroll
      for (int sj = 0; sj < 4; ++sj)
        if (j0 + sj * 16 + r15 > SEQ - 1) s[sj] = (f32x4){-1e30f, -1e30f, -1e30f, -1e30f};

      // P = exp2(S) unshifted; accumulate per-lane row sums
#pragma unroll
      for (int sj = 0; sj < 4; ++sj)
#pragma unroll
        for (int r = 0; r < 4; ++r) {
          float e = __builtin_amdgcn_exp2f(s[sj][r]);
          s[sj][r] = e;
          lrow[g][r] += e;
        }

      // P: C/D layout -> wave-private LDS -> A layout (same-wave RAW; DS in-order)
#pragma unroll
      for (int sj = 0; sj < 4; ++sj)
#pragma unroll
        for (int r = 0; r < 4; ++r)
          Pw[(quad * 4 + r) * 72 + sj * 16 + r15] = (bf16)s[sj][r];
      asm volatile("s_waitcnt lgkmcnt(0)" ::: "memory");

      // O += P V
#pragma unroll
      for (int kc = 0; kc < 2; ++kc) {
        bf16x8 pf = *(const bf16x8*)(Pw + r15 * 72 + kc * 32 + quad * 8);
#pragma unroll
        for (int sd = 0; sd < 4; ++sd) {
          bf16x8 vf = *(const bf16x8*)(Vt + (sd * 16 + r15) * 72 + kc * 32 + quad * 8);
          oacc[g][sd] = MFMA_BF16(pf, vf, oacc[g][sd]);
        }
      }
    }
  }

  // ONE shuffle reduction per group: row sum over the 16 lanes of each quad-group
#pragma unroll
  for (int g = 0; g < 2; ++g)
#pragma unroll
    for (int r = 0; r < 4; ++r) {
      float rs = lrow[g][r];
      rs += __shfl_xor(rs, 1);
      rs += __shfl_xor(rs, 2);
      rs += __shfl_xor(rs, 4);
      rs += __shfl_xor(rs, 8);
      lrow[g][r] = rs;
    }

  // write O -> attn_out [b*577+n][h*64+d] bf16 row-major
#pragma unroll
  for (int g = 0; g < 2; ++g)
#pragma unroll
    for (int r = 0; r < 4; ++r) {
      int orow = qt * 128 + wid * 32 + g * 16 + quad * 4 + r;
      if (orow < SEQ) {
        float inv = 1.0f / lrow[g][r];
        size_t rowoff = ((size_t)(b_ * SEQ + orow)) * CH + h * DHD;
#pragma unroll
        for (int sd = 0; sd < 4; ++sd)
          ob[rowoff + sd * 16 + r15] = (bf16)(oacc[g][sd][r] * inv);
      }
    }
}

extern "C" void kernel_launch(void* const* d_in, const int* in_sizes, int n_in,
                              void* d_out, int out_size, void* d_ws, size_t ws_size,
                              hipStream_t stream) {
  const float* x      = (const float*)d_in[0];
  const float* qkv_w  = (const float*)d_in[1];
  const float* qkv_b  = (const float*)d_in[2];
  const float* proj_w = (const float*)d_in[3];
  const float* proj_b = (const float*)d_in[4];
  float* out = (float*)d_out;

  char* w = (char*)d_ws;
  // workspace layout (bytes), total 117,325,824:
  bf16* xb  = (bf16*)(w);               // [18464,768] x_bf16, reused as attn_out
  bf16* wqp = (bf16*)(w + 28360704);    // qkv_w bf16; later aliased by proj_w bf16
  bf16* qrm = (bf16*)(w + 31899648);    // [18464,768] scaled Q
  bf16* krm = (bf16*)(w + 60260352);    // [18464,768] K
  bf16* vtb = (bf16*)(w + 88621056);    // [32,12,64,584] V^T
  // GEMM m-tail reads spill into the wqp region: finite, discarded.

  cvt_bf16<<<(MROWS * CH / 4 + 255) / 256, 256, 0, stream>>>(x, xb, MROWS * CH);
  cvt_bf16<<<(NQKV * CH / 4 + 255) / 256, 256, 0, stream>>>(qkv_w, wqp, NQKV * CH);
  pad_v<<<(BB * NH * DHD + 255) / 256, 256, 0, stream>>>(vtb);

  gemm_qkv<<<dim3(NQKV / 128, 145), 256, 0, stream>>>(
      xb, wqp, qkv_b, qrm, krm, vtb);

  attn_kernel<<<dim3(5, BB * NH), 256, 0, stream>>>(qrm, krm, vtb, xb);

  // proj weights convert AFTER attention (stream-ordered) so it can alias wqp
  cvt_bf16<<<(CH * CH / 4 + 255) / 256, 256, 0, stream>>>(proj_w, wqp, CH * CH);

  gemm_proj<<<dim3(CH / 256, 73), 512, 0, stream>>>(xb, wqp, proj_b, out);
}

// Round 6
// 361.200 us; speedup vs baseline: 1.4155x; 1.0429x over previous
//
#include <hip/hip_runtime.h>

typedef __bf16 bf16;
typedef __attribute__((ext_vector_type(4))) __bf16 bf16x4;
typedef __attribute__((ext_vector_type(8))) __bf16 bf16x8;
typedef __attribute__((ext_vector_type(4))) float f32x4;

#define MFMA_BF16(A_, B_, C_) __builtin_amdgcn_mfma_f32_16x16x32_bf16(A_, B_, C_, 0, 0, 0)

// Problem dims
#define BB    32
#define SEQ   577
#define CH    768
#define NH    12
#define DHD   64
#define MROWS (BB * SEQ)   // 18464
#define NQKV  2304
#define SEQP  584          // V^T row stride (73*8)
// q scale folded with log2(e): softmax computed in base-2 domain
#define QSCALE 0.1803368801111204f

#define NSTEP 24           // K-steps of 32 for the 256^2 proj GEMM (768 = 24*32)

// ---- async global->LDS 16B (wave-uniform LDS base + lane*16, per guide §5) ----
__device__ __forceinline__ void async_ld16(const bf16* g, bf16* l) {
  __builtin_amdgcn_global_load_lds(
      (const __attribute__((address_space(1))) void*)g,
      (__attribute__((address_space(3))) void*)l, 16, 0, 0);
}

// ---- fp32 -> bf16 convert ----
__global__ __launch_bounds__(256) void cvt_bf16(const float* __restrict__ src,
                                                bf16* __restrict__ dst, int n) {
  int idx = (blockIdx.x * 256 + threadIdx.x) * 4;
  if (idx >= n) return;
  float4 v = *(const float4*)(src + idx);
  bf16x4 o = {(bf16)v.x, (bf16)v.y, (bf16)v.z, (bf16)v.w};
  *(bf16x4*)(dst + idx) = o;
}

// ---- zero the 7-element pad of each V^T row (j in [577,584)) so attention's
// staged V reads at jst=576 see finite values regardless of workspace state.
__global__ __launch_bounds__(256) void pad_v(bf16* __restrict__ vt) {
  int r = blockIdx.x * 256 + threadIdx.x;
  if (r < BB * NH * DHD) {
    bf16* p = vt + (size_t)r * SEQP + SEQ;
#pragma unroll
    for (int i = 0; i < 7; ++i) p[i] = (bf16)0.f;
  }
}

// ---- 128x128x(K=768) bf16 MFMA GEMM (qkv), R0-proven structure (145us) ----
// Double-buffered single-barrier K-loop: loads for step k+1 issued right after the
// barrier, drained by the NEXT barrier -> each drain has a full compute phase of slack.
// Grid: x = n-tiles (fast -> A m-tile reused across consecutive blocks), y = m-tiles.
// qkv epilogue: q -> qrm [M,768] (scaled), k -> krm [M,768], v -> vt [B,H,64,SEQP]
__global__ __launch_bounds__(256, 2)
void gemm_qkv(const bf16* __restrict__ A, const bf16* __restrict__ W,
              const float* __restrict__ bias,
              bf16* __restrict__ qrm, bf16* __restrict__ krm, bf16* __restrict__ vt) {
  __shared__ bf16 As[2][128 * 32];
  __shared__ bf16 Bs[2][128 * 32];
  const int tid = threadIdx.x, lane = tid & 63, wid = tid >> 6;
  const int quad = lane >> 4, r15 = lane & 15;
  const int m0 = blockIdx.y * 128, n0 = blockIdx.x * 128;
  const int waveM = wid & 1, waveN = wid >> 1;

  // staging: 512 16B chunks per tile; XOR chunk swizzle -> fragment ds_read_b128 2-way (free)
  const bf16* aSrc[2];
  const bf16* bSrc[2];
  for (int c = 0; c < 2; ++c) {
    int q = wid * 128 + c * 64 + lane;
    int row = q >> 2;
    int sw = (row ^ (row >> 2)) & 3;
    int kc = (q & 3) ^ sw;
    aSrc[c] = A + (size_t)(m0 + row) * CH + kc * 8;
    bSrc[c] = W + (size_t)(n0 + row) * CH + kc * 8;
  }

  f32x4 acc[4][4];
#pragma unroll
  for (int i = 0; i < 4; ++i)
#pragma unroll
    for (int j = 0; j < 4; ++j) acc[i][j] = (f32x4){0.f, 0.f, 0.f, 0.f};

#define GSTAGE(K0, BUF)                                                   \
  {                                                                       \
    _Pragma("unroll") for (int c = 0; c < 2; ++c) {                       \
      async_ld16(aSrc[c] + (K0), &As[BUF][(wid * 128 + c * 64) * 8]);     \
      async_ld16(bSrc[c] + (K0), &Bs[BUF][(wid * 128 + c * 64) * 8]);     \
    }                                                                     \
  }

#define GCOMPUTE(BUF)                                                     \
  {                                                                       \
    bf16x8 af[4], bfr[4];                                                 \
    _Pragma("unroll") for (int s = 0; s < 4; ++s) {                       \
      int rowA = waveM * 64 + s * 16 + r15;                               \
      int ca = quad ^ ((rowA ^ (rowA >> 2)) & 3);                         \
      af[s] = *(const bf16x8*)(&As[BUF][rowA * 32 + ca * 8]);             \
      int rowB = waveN * 64 + s * 16 + r15;                               \
      int cb = quad ^ ((rowB ^ (rowB >> 2)) & 3);                         \
      bfr[s] = *(const bf16x8*)(&Bs[BUF][rowB * 32 + cb * 8]);            \
    }                                                                     \
    _Pragma("unroll") for (int sm = 0; sm < 4; ++sm)                      \
      _Pragma("unroll") for (int sn = 0; sn < 4; ++sn)                    \
        acc[sm][sn] = MFMA_BF16(af[sm], bfr[sn], acc[sm][sn]);            \
  }

  GSTAGE(0, 0);
  for (int k0 = 0; k0 < CH; k0 += 64) {
    __syncthreads();                       // drains buf0 loads (issued prev iter / prologue)
    GSTAGE(k0 + 32, 1);                    // overlaps compute on buf0
    GCOMPUTE(0);
    __syncthreads();                       // drains buf1 loads; all waves done with buf0
    if (k0 + 64 < CH) GSTAGE(k0 + 64, 0);  // overlaps compute on buf1
    GCOMPUTE(1);
  }

  // epilogue: C/D layout row=(lane>>4)*4+reg, col=lane&15 (verified m89/m91)
  int t = (n0 >= 1536) ? 2 : (n0 >= 768 ? 1 : 0);  // 128-tiles never straddle 768
#pragma unroll
  for (int sn = 0; sn < 4; ++sn) {
    int gn = n0 + waveN * 64 + sn * 16 + r15;
    float bv = bias[gn];
    int col = gn - t * CH;  // [0,768)
    int h = col >> 6, d = col & 63;
#pragma unroll
    for (int sm = 0; sm < 4; ++sm) {
      int gmBase = m0 + waveM * 64 + sm * 16 + quad * 4;
#pragma unroll
      for (int r = 0; r < 4; ++r) {
        int gm = gmBase + r;
        if (gm < MROWS) {
          float v = acc[sm][sn][r] + bv;
          if (t == 0) {
            qrm[(size_t)gm * CH + col] = (bf16)(v * QSCALE);
          } else if (t == 1) {
            krm[(size_t)gm * CH + col] = (bf16)v;
          } else {
            int b_ = gm / SEQ;
            int n_ = gm - b_ * SEQ;
            vt[((size_t)(b_ * NH + h) * DHD + d) * SEQP + n_] = (bf16)v;
          }
        }
      }
    }
  }
}
#undef GSTAGE
#undef GCOMPUTE

// ---- 256x256x(K=768) proj GEMM, R3-proven (single 219-block round). ----
// Counted-vmcnt pipeline, 4 LDS buffers, prefetch distance 2, one raw s_barrier
// per 32-K step.
__global__ __launch_bounds__(512, 2)
void gemm_proj(const bf16* __restrict__ A, const bf16* __restrict__ W,
               const float* __restrict__ bias, float* __restrict__ out) {
  __shared__ bf16 As[4][256 * 32];  // [buf][row*32 + chunk2*8], 16 KiB each
  __shared__ bf16 Bs[4][256 * 32];
  const int tid = threadIdx.x, lane = tid & 63, wid = tid >> 6;
  const int quad = lane >> 4, r15 = lane & 15;

  const int nbx = (int)gridDim.x;
  const int nwg = nbx * (int)gridDim.y;
  int bid = (int)blockIdx.y * nbx + (int)blockIdx.x;
  int q8 = nwg >> 3, r8 = nwg & 7;
  int xcd = bid & 7, sub = bid >> 3;
  int wg = (xcd < r8 ? xcd * (q8 + 1) : r8 * (q8 + 1) + (xcd - r8) * q8) + sub;
  const int m0 = (wg / nbx) * 256, n0 = (wg % nbx) * 256;

  const int rm = (wid >> 2) * 128;  // wave row base (2 waves in M)
  const int rn = (wid & 3) * 64;    // wave col base (4 waves in N)

  int aOff[2], bOff[2];
#pragma unroll
  for (int i = 0; i < 2; ++i) {
    int slot = i * 512 + tid;
    int row = slot >> 2, pc2 = slot & 3;
    int gc2 = pc2 ^ ((row ^ (row >> 2)) & 3);
    aOff[i] = (m0 + row) * CH + gc2 * 8;
    bOff[i] = (n0 + row) * CH + gc2 * 8;
  }

  f32x4 acc[8][4];
#pragma unroll
  for (int i = 0; i < 8; ++i)
#pragma unroll
    for (int j = 0; j < 4; ++j) acc[i][j] = (f32x4){0.f, 0.f, 0.f, 0.f};

#define ISSUE2(S)                                                              \
  {                                                                            \
    const int kb_ = (S) * 32;                                                  \
    const int bf_ = (S) & 3;                                                   \
    _Pragma("unroll") for (int i = 0; i < 2; ++i) {                            \
      async_ld16(A + aOff[i] + kb_, &As[bf_][(i * 512 + tid) * 8]);            \
      async_ld16(W + bOff[i] + kb_, &Bs[bf_][(i * 512 + tid) * 8]);            \
    }                                                                          \
  }

#define COMPUTE2(BF)                                                           \
  {                                                                            \
    bf16x8 bfr[4], afr[8];                                                     \
    _Pragma("unroll") for (int sn = 0; sn < 4; ++sn) {                         \
      int fr = rn + sn * 16 + r15;                                             \
      int pc2 = quad ^ ((fr ^ (fr >> 2)) & 3);                                 \
      bfr[sn] = *(const bf16x8*)(&Bs[BF][fr * 32 + pc2 * 8]);                  \
    }                                                                          \
    _Pragma("unroll") for (int sm = 0; sm < 8; ++sm) {                         \
      int fr = rm + sm * 16 + r15;                                             \
      int pc2 = quad ^ ((fr ^ (fr >> 2)) & 3);                                 \
      afr[sm] = *(const bf16x8*)(&As[BF][fr * 32 + pc2 * 8]);                  \
    }                                                                          \
    _Pragma("unroll") for (int sm = 0; sm < 8; ++sm)                           \
      _Pragma("unroll") for (int sn = 0; sn < 4; ++sn)                         \
        acc[sm][sn] = MFMA_BF16(afr[sm], bfr[sn], acc[sm][sn]);                \
  }

  ISSUE2(0);
  ISSUE2(1);
  for (int s = 0; s < NSTEP; ++s) {
    if (s < NSTEP - 2) {
      ISSUE2(s + 2);
      asm volatile("s_waitcnt vmcnt(8)" ::: "memory");
    } else if (s == NSTEP - 2) {
      asm volatile("s_waitcnt vmcnt(4)" ::: "memory");
    } else {
      asm volatile("s_waitcnt vmcnt(0)" ::: "memory");
    }
    __builtin_amdgcn_s_barrier();
    asm volatile("" ::: "memory");
    COMPUTE2(s & 3);
  }

  // epilogue: bias + fp32 out
#pragma unroll
  for (int sn = 0; sn < 4; ++sn) {
    int gn = n0 + rn + sn * 16 + r15;
    float bv = bias[gn];
#pragma unroll
    for (int sm = 0; sm < 8; ++sm) {
      int gmBase = m0 + rm + sm * 16 + quad * 4;
#pragma unroll
      for (int r = 0; r < 4; ++r) {
        int gm = gmBase + r;
        if (gm < MROWS) out[(size_t)gm * CH + gn] = acc[sm][sn][r] + bv;
      }
    }
  }
}
#undef ISSUE2
#undef COMPUTE2

// ---- flash attention, NO-MAX softmax, base-2 domain. R6: SWAPPED QK^T ----
// Computes S^T = mfma(K, Q) so the C/D accumulator holds contiguous-j per lane:
//   s[sj][r] = S^T[j = j0+sj*16+quad*4+r][m = r15]
// Payoffs vs R5 (attn was LDS-pipe-bound, ~666 cyc/wave/tile):
//   - P-write: 16 scalar ds_write_b16 per group -> 4 packed ds_write_b64
//     (pack along r, contiguous in the [m][j] P layout)
//   - K-frag reads hoisted: ONE pass over sj feeds BOTH q-row groups (16->8/tile)
//   - V-frag reads shared by both groups inside the PV loop (16->8/tile)
//   - row-sum: one scalar per lane (its 16 j-values, all same m=r15), reduced
//     via shfl_xor(16,32) across quads; redistributed once at the end.
// ~332 cyc/wave/tile of LDS pipe (-50%). VGPR ~115 (s0+s1 live) -> (256,4).
__global__ __launch_bounds__(256, 4)
void attn_kernel(const bf16* __restrict__ qrm, const bf16* __restrict__ krm,
                 const bf16* __restrict__ vt, bf16* __restrict__ ob) {
  __shared__ bf16 Ks[64 * 72];         // K tile [j][d] pad 72
  __shared__ bf16 Vt[64 * 72];         // V^T tile [d][j] pad 72
  __shared__ bf16 Ps[4][2][16 * 72];   // per-wave, per-group private P [m][j] pad 72
  const int tid = threadIdx.x, lane = tid & 63, wid = tid >> 6;
  const int quad = lane >> 4, r15 = lane & 15;
  const int qt = blockIdx.x, bh = blockIdx.y;
  const int b_ = bh / NH, h = bh - b_ * NH;
  const bf16* vtb = vt + (size_t)bh * DHD * SEQP;

  // Q fragments resident for both row groups. Q is now the MFMA *B* operand:
  // B-frag layout n=lane&15 (= q-row within group), k=quad*8+j. Same read as before.
  bf16x8 qf[2][2];
#pragma unroll
  for (int g = 0; g < 2; ++g) {
    int qrow = qt * 128 + wid * 32 + g * 16 + r15;
    if (qrow > SEQ - 1) qrow = SEQ - 1;
    const bf16* qp = qrm + (size_t)(b_ * SEQ + qrow) * CH + h * DHD + quad * 8;
    qf[g][0] = *(const bf16x8*)qp;
    qf[g][1] = *(const bf16x8*)(qp + 32);
  }

  f32x4 oacc[2][4];
#pragma unroll
  for (int g = 0; g < 2; ++g)
#pragma unroll
    for (int i = 0; i < 4; ++i) oacc[g][i] = (f32x4){0.f, 0.f, 0.f, 0.f};
  float lrow0 = 0.f, lrow1 = 0.f;  // per-lane partial row sum (row m = r15)

  bf16* P0 = &Ps[wid][0][0];
  bf16* P1 = &Ps[wid][1][0];

  for (int j0 = 0; j0 < SEQ; j0 += 64) {
    __syncthreads();  // all waves done reading Ks/Vt of previous tile
    // stage K [64 j x 64 d] and V^T [64 d x 64 j]: 512 x 16B chunks each
#pragma unroll
    for (int c = 0; c < 2; ++c) {
      int sid = c * 256 + tid;           // [0,512)
      int row = sid >> 3, cc = sid & 7;  // row in [0,64), chunk in [0,8)
      int jr = j0 + row;
      if (jr > SEQ - 1) jr = SEQ - 1;
      *(bf16x8*)(Ks + row * 72 + cc * 8) =
          *(const bf16x8*)(krm + (size_t)(b_ * SEQ + jr) * CH + h * DHD + cc * 8);
      int jst = j0 + cc * 8;             // V^T chunk start; clamp keeps reads in-bounds,
      if (jst > SEQ - 1) jst = SEQ - 1;  // pad cols zeroed by pad_v; P=0 there anyway
      *(bf16x8*)(Vt + row * 72 + cc * 8) = *(const bf16x8*)(vtb + (size_t)row * SEQP + jst);
    }
    __syncthreads();

    // S^T = K Q^T for BOTH groups in one pass over sj (K-frags read once).
    // A-frag = K rows sj*16+r15 (i=r15), k=quad*8+kk  -> same LDS addresses as before.
    f32x4 s0[4], s1[4];
#pragma unroll
    for (int sj = 0; sj < 4; ++sj) {
      bf16x8 kf0 = *(const bf16x8*)(Ks + (sj * 16 + r15) * 72 + quad * 8);
      bf16x8 kf1 = *(const bf16x8*)(Ks + (sj * 16 + r15) * 72 + 32 + quad * 8);
      f32x4 z = (f32x4){0.f, 0.f, 0.f, 0.f};
      s0[sj] = MFMA_BF16(kf0, qf[0][0], z);
      s0[sj] = MFMA_BF16(kf1, qf[0][1], s0[sj]);
      s1[sj] = MFMA_BF16(kf0, qf[1][0], z);
      s1[sj] = MFMA_BF16(kf1, qf[1][1], s1[sj]);
    }

    // P = exp2(S) with OOB-j zeroed directly (j = j0 + sj*16 + quad*4 + r).
#pragma unroll
    for (int sj = 0; sj < 4; ++sj)
#pragma unroll
      for (int r = 0; r < 4; ++r) {
        int j = j0 + sj * 16 + quad * 4 + r;
        float e0 = (j <= SEQ - 1) ? __builtin_amdgcn_exp2f(s0[sj][r]) : 0.f;
        float e1 = (j <= SEQ - 1) ? __builtin_amdgcn_exp2f(s1[sj][r]) : 0.f;
        s0[sj][r] = e0; lrow0 += e0;
        s1[sj][r] = e1; lrow1 += e1;
      }

    // P store [m][j]: lane's 4 regs are contiguous in j -> packed b64 writes.
#pragma unroll
    for (int sj = 0; sj < 4; ++sj) {
      bf16x4 p0 = {(bf16)s0[sj][0], (bf16)s0[sj][1], (bf16)s0[sj][2], (bf16)s0[sj][3]};
      bf16x4 p1 = {(bf16)s1[sj][0], (bf16)s1[sj][1], (bf16)s1[sj][2], (bf16)s1[sj][3]};
      *(bf16x4*)(P0 + r15 * 72 + sj * 16 + quad * 4) = p0;
      *(bf16x4*)(P1 + r15 * 72 + sj * 16 + quad * 4) = p1;
    }
    asm volatile("s_waitcnt lgkmcnt(0)" ::: "memory");  // wave-private RAW

    // O += P V ; V-frags read ONCE, shared by both groups.
#pragma unroll
    for (int kc = 0; kc < 2; ++kc) {
      bf16x8 pf0 = *(const bf16x8*)(P0 + r15 * 72 + kc * 32 + quad * 8);
      bf16x8 pf1 = *(const bf16x8*)(P1 + r15 * 72 + kc * 32 + quad * 8);
#pragma unroll
      for (int sd = 0; sd < 4; ++sd) {
        bf16x8 vf = *(const bf16x8*)(Vt + (sd * 16 + r15) * 72 + kc * 32 + quad * 8);
        oacc[0][sd] = MFMA_BF16(pf0, vf, oacc[0][sd]);
        oacc[1][sd] = MFMA_BF16(pf1, vf, oacc[1][sd]);
      }
    }
  }

  // Row sums: reduce across the 4 lanes sharing r15 (quads) -> full sum at every lane.
  lrow0 += __shfl_xor(lrow0, 16);
  lrow0 += __shfl_xor(lrow0, 32);
  lrow1 += __shfl_xor(lrow1, 16);
  lrow1 += __shfl_xor(lrow1, 32);

  // write O -> attn_out [b*577+n][h*64+d]; O C/D layout: row m=quad*4+r, col d=sd*16+r15.
  // Row sum for m lives at lanes with r15==m -> fetch via one shuffle (src lane = m).
#pragma unroll
  for (int g = 0; g < 2; ++g) {
    float lr = (g == 0) ? lrow0 : lrow1;
#pragma unroll
    for (int r = 0; r < 4; ++r) {
      int m = quad * 4 + r;
      float rs = __shfl(lr, m);
      int orow = qt * 128 + wid * 32 + g * 16 + m;
      if (orow < SEQ) {
        float inv = 1.0f / rs;
        size_t rowoff = ((size_t)(b_ * SEQ + orow)) * CH + h * DHD;
#pragma unroll
        for (int sd = 0; sd < 4; ++sd)
          ob[rowoff + sd * 16 + r15] = (bf16)(oacc[g][sd][r] * inv);
      }
    }
  }
}

extern "C" void kernel_launch(void* const* d_in, const int* in_sizes, int n_in,
                              void* d_out, int out_size, void* d_ws, size_t ws_size,
                              hipStream_t stream) {
  const float* x      = (const float*)d_in[0];
  const float* qkv_w  = (const float*)d_in[1];
  const float* qkv_b  = (const float*)d_in[2];
  const float* proj_w = (const float*)d_in[3];
  const float* proj_b = (const float*)d_in[4];
  float* out = (float*)d_out;

  char* w = (char*)d_ws;
  // workspace layout (bytes), total 117,325,824:
  bf16* xb  = (bf16*)(w);               // [18464,768] x_bf16, reused as attn_out
  bf16* wqp = (bf16*)(w + 28360704);    // qkv_w bf16; later aliased by proj_w bf16
  bf16* qrm = (bf16*)(w + 31899648);    // [18464,768] scaled Q
  bf16* krm = (bf16*)(w + 60260352);    // [18464,768] K
  bf16* vtb = (bf16*)(w + 88621056);    // [32,12,64,584] V^T
  // GEMM m-tail reads spill into the wqp region: finite, discarded.

  cvt_bf16<<<(MROWS * CH / 4 + 255) / 256, 256, 0, stream>>>(x, xb, MROWS * CH);
  cvt_bf16<<<(NQKV * CH / 4 + 255) / 256, 256, 0, stream>>>(qkv_w, wqp, NQKV * CH);
  pad_v<<<(BB * NH * DHD + 255) / 256, 256, 0, stream>>>(vtb);

  gemm_qkv<<<dim3(NQKV / 128, 145), 256, 0, stream>>>(
      xb, wqp, qkv_b, qrm, krm, vtb);

  attn_kernel<<<dim3(5, BB * NH), 256, 0, stream>>>(qrm, krm, vtb, xb);

  // proj weights convert AFTER attention (stream-ordered) so it can alias wqp
  cvt_bf16<<<(CH * CH / 4 + 255) / 256, 256, 0, stream>>>(proj_w, wqp, CH * CH);

  gemm_proj<<<dim3(CH / 256, 73), 512, 0, stream>>>(xb, wqp, proj_b, out);
}

// Round 7
// 350.254 us; speedup vs baseline: 1.4598x; 1.0313x over previous
//
#include <hip/hip_runtime.h>

typedef __bf16 bf16;
typedef __attribute__((ext_vector_type(4))) __bf16 bf16x4;
typedef __attribute__((ext_vector_type(8))) __bf16 bf16x8;
typedef __attribute__((ext_vector_type(4))) float f32x4;

#define MFMA_BF16(A_, B_, C_) __builtin_amdgcn_mfma_f32_16x16x32_bf16(A_, B_, C_, 0, 0, 0)

// Problem dims
#define BB    32
#define SEQ   577
#define CH    768
#define NH    12
#define DHD   64
#define MROWS (BB * SEQ)   // 18464
#define NQKV  2304
#define SEQP  584          // V^T row stride (73*8)
// q scale folded with log2(e): softmax computed in base-2 domain
#define QSCALE 0.1803368801111204f

#define NSTEP 24           // K-steps of 32 for the 256^2 proj GEMM (768 = 24*32)
#define NJT   10           // attn j-tiles (577 = 9*64 + 1)

// ---- async global->LDS 16B (wave-uniform LDS base + lane*16, per guide §5) ----
__device__ __forceinline__ void async_ld16(const bf16* g, bf16* l) {
  __builtin_amdgcn_global_load_lds(
      (const __attribute__((address_space(1))) void*)g,
      (__attribute__((address_space(3))) void*)l, 16, 0, 0);
}

// ---- fp32 -> bf16 convert ----
__global__ __launch_bounds__(256) void cvt_bf16(const float* __restrict__ src,
                                                bf16* __restrict__ dst, int n) {
  int idx = (blockIdx.x * 256 + threadIdx.x) * 4;
  if (idx >= n) return;
  float4 v = *(const float4*)(src + idx);
  bf16x4 o = {(bf16)v.x, (bf16)v.y, (bf16)v.z, (bf16)v.w};
  *(bf16x4*)(dst + idx) = o;
}

// ---- zero the 7-element pad of each V^T row (j in [577,584)) so attention's
// staged V reads at clamped chunk start 576 see zeros beyond j=576.
__global__ __launch_bounds__(256) void pad_v(bf16* __restrict__ vt) {
  int r = blockIdx.x * 256 + threadIdx.x;
  if (r < BB * NH * DHD) {
    bf16* p = vt + (size_t)r * SEQP + SEQ;
#pragma unroll
    for (int i = 0; i < 7; ++i) p[i] = (bf16)0.f;
  }
}

// ---- 128x128x(K=768) bf16 MFMA GEMM (qkv), R0-proven structure (145us) ----
// Double-buffered single-barrier K-loop: loads for step k+1 issued right after the
// barrier, drained by the NEXT barrier -> each drain has a full compute phase of slack.
// Grid: x = n-tiles (fast -> A m-tile reused across consecutive blocks), y = m-tiles.
// qkv epilogue: q -> qrm [M,768] (scaled), k -> krm [M,768], v -> vt [B,H,64,SEQP]
__global__ __launch_bounds__(256, 2)
void gemm_qkv(const bf16* __restrict__ A, const bf16* __restrict__ W,
              const float* __restrict__ bias,
              bf16* __restrict__ qrm, bf16* __restrict__ krm, bf16* __restrict__ vt) {
  __shared__ bf16 As[2][128 * 32];
  __shared__ bf16 Bs[2][128 * 32];
  const int tid = threadIdx.x, lane = tid & 63, wid = tid >> 6;
  const int quad = lane >> 4, r15 = lane & 15;
  const int m0 = blockIdx.y * 128, n0 = blockIdx.x * 128;
  const int waveM = wid & 1, waveN = wid >> 1;

  // staging: 512 16B chunks per tile; XOR chunk swizzle -> fragment ds_read_b128 2-way (free)
  const bf16* aSrc[2];
  const bf16* bSrc[2];
  for (int c = 0; c < 2; ++c) {
    int q = wid * 128 + c * 64 + lane;
    int row = q >> 2;
    int sw = (row ^ (row >> 2)) & 3;
    int kc = (q & 3) ^ sw;
    aSrc[c] = A + (size_t)(m0 + row) * CH + kc * 8;
    bSrc[c] = W + (size_t)(n0 + row) * CH + kc * 8;
  }

  f32x4 acc[4][4];
#pragma unroll
  for (int i = 0; i < 4; ++i)
#pragma unroll
    for (int j = 0; j < 4; ++j) acc[i][j] = (f32x4){0.f, 0.f, 0.f, 0.f};

#define GSTAGE(K0, BUF)                                                   \
  {                                                                       \
    _Pragma("unroll") for (int c = 0; c < 2; ++c) {                       \
      async_ld16(aSrc[c] + (K0), &As[BUF][(wid * 128 + c * 64) * 8]);     \
      async_ld16(bSrc[c] + (K0), &Bs[BUF][(wid * 128 + c * 64) * 8]);     \
    }                                                                     \
  }

#define GCOMPUTE(BUF)                                                     \
  {                                                                       \
    bf16x8 af[4], bfr[4];                                                 \
    _Pragma("unroll") for (int s = 0; s < 4; ++s) {                       \
      int rowA = waveM * 64 + s * 16 + r15;                               \
      int ca = quad ^ ((rowA ^ (rowA >> 2)) & 3);                         \
      af[s] = *(const bf16x8*)(&As[BUF][rowA * 32 + ca * 8]);             \
      int rowB = waveN * 64 + s * 16 + r15;                               \
      int cb = quad ^ ((rowB ^ (rowB >> 2)) & 3);                         \
      bfr[s] = *(const bf16x8*)(&Bs[BUF][rowB * 32 + cb * 8]);            \
    }                                                                     \
    _Pragma("unroll") for (int sm = 0; sm < 4; ++sm)                      \
      _Pragma("unroll") for (int sn = 0; sn < 4; ++sn)                    \
        acc[sm][sn] = MFMA_BF16(af[sm], bfr[sn], acc[sm][sn]);            \
  }

  GSTAGE(0, 0);
  for (int k0 = 0; k0 < CH; k0 += 64) {
    __syncthreads();                       // drains buf0 loads (issued prev iter / prologue)
    GSTAGE(k0 + 32, 1);                    // overlaps compute on buf0
    GCOMPUTE(0);
    __syncthreads();                       // drains buf1 loads; all waves done with buf0
    if (k0 + 64 < CH) GSTAGE(k0 + 64, 0);  // overlaps compute on buf1
    GCOMPUTE(1);
  }

  // epilogue: C/D layout row=(lane>>4)*4+reg, col=lane&15 (verified m89/m91)
  int t = (n0 >= 1536) ? 2 : (n0 >= 768 ? 1 : 0);  // 128-tiles never straddle 768
#pragma unroll
  for (int sn = 0; sn < 4; ++sn) {
    int gn = n0 + waveN * 64 + sn * 16 + r15;
    float bv = bias[gn];
    int col = gn - t * CH;  // [0,768)
    int h = col >> 6, d = col & 63;
#pragma unroll
    for (int sm = 0; sm < 4; ++sm) {
      int gmBase = m0 + waveM * 64 + sm * 16 + quad * 4;
#pragma unroll
      for (int r = 0; r < 4; ++r) {
        int gm = gmBase + r;
        if (gm < MROWS) {
          float v = acc[sm][sn][r] + bv;
          if (t == 0) {
            qrm[(size_t)gm * CH + col] = (bf16)(v * QSCALE);
          } else if (t == 1) {
            krm[(size_t)gm * CH + col] = (bf16)v;
          } else {
            int b_ = gm / SEQ;
            int n_ = gm - b_ * SEQ;
            vt[((size_t)(b_ * NH + h) * DHD + d) * SEQP + n_] = (bf16)v;
          }
        }
      }
    }
  }
}
#undef GSTAGE
#undef GCOMPUTE

// ---- 256x256x(K=768) proj GEMM, R3-proven (single 219-block round). ----
// Counted-vmcnt pipeline, 4 LDS buffers, prefetch distance 2, one raw s_barrier
// per 32-K step.
__global__ __launch_bounds__(512, 2)
void gemm_proj(const bf16* __restrict__ A, const bf16* __restrict__ W,
               const float* __restrict__ bias, float* __restrict__ out) {
  __shared__ bf16 As[4][256 * 32];  // [buf][row*32 + chunk2*8], 16 KiB each
  __shared__ bf16 Bs[4][256 * 32];
  const int tid = threadIdx.x, lane = tid & 63, wid = tid >> 6;
  const int quad = lane >> 4, r15 = lane & 15;

  const int nbx = (int)gridDim.x;
  const int nwg = nbx * (int)gridDim.y;
  int bid = (int)blockIdx.y * nbx + (int)blockIdx.x;
  int q8 = nwg >> 3, r8 = nwg & 7;
  int xcd = bid & 7, sub = bid >> 3;
  int wg = (xcd < r8 ? xcd * (q8 + 1) : r8 * (q8 + 1) + (xcd - r8) * q8) + sub;
  const int m0 = (wg / nbx) * 256, n0 = (wg % nbx) * 256;

  const int rm = (wid >> 2) * 128;  // wave row base (2 waves in M)
  const int rn = (wid & 3) * 64;    // wave col base (4 waves in N)

  int aOff[2], bOff[2];
#pragma unroll
  for (int i = 0; i < 2; ++i) {
    int slot = i * 512 + tid;
    int row = slot >> 2, pc2 = slot & 3;
    int gc2 = pc2 ^ ((row ^ (row >> 2)) & 3);
    aOff[i] = (m0 + row) * CH + gc2 * 8;
    bOff[i] = (n0 + row) * CH + gc2 * 8;
  }

  f32x4 acc[8][4];
#pragma unroll
  for (int i = 0; i < 8; ++i)
#pragma unroll
    for (int j = 0; j < 4; ++j) acc[i][j] = (f32x4){0.f, 0.f, 0.f, 0.f};

#define ISSUE2(S)                                                              \
  {                                                                            \
    const int kb_ = (S) * 32;                                                  \
    const int bf_ = (S) & 3;                                                   \
    _Pragma("unroll") for (int i = 0; i < 2; ++i) {                            \
      async_ld16(A + aOff[i] + kb_, &As[bf_][(i * 512 + tid) * 8]);            \
      async_ld16(W + bOff[i] + kb_, &Bs[bf_][(i * 512 + tid) * 8]);            \
    }                                                                          \
  }

#define COMPUTE2(BF)                                                           \
  {                                                                            \
    bf16x8 bfr[4], afr[8];                                                     \
    _Pragma("unroll") for (int sn = 0; sn < 4; ++sn) {                         \
      int fr = rn + sn * 16 + r15;                                             \
      int pc2 = quad ^ ((fr ^ (fr >> 2)) & 3);                                 \
      bfr[sn] = *(const bf16x8*)(&Bs[BF][fr * 32 + pc2 * 8]);                  \
    }                                                                          \
    _Pragma("unroll") for (int sm = 0; sm < 8; ++sm) {                         \
      int fr = rm + sm * 16 + r15;                                             \
      int pc2 = quad ^ ((fr ^ (fr >> 2)) & 3);                                 \
      afr[sm] = *(const bf16x8*)(&As[BF][fr * 32 + pc2 * 8]);                  \
    }                                                                          \
    _Pragma("unroll") for (int sm = 0; sm < 8; ++sm)                           \
      _Pragma("unroll") for (int sn = 0; sn < 4; ++sn)                         \
        acc[sm][sn] = MFMA_BF16(afr[sm], bfr[sn], acc[sm][sn]);                \
  }

  ISSUE2(0);
  ISSUE2(1);
  for (int s = 0; s < NSTEP; ++s) {
    if (s < NSTEP - 2) {
      ISSUE2(s + 2);
      asm volatile("s_waitcnt vmcnt(8)" ::: "memory");
    } else if (s == NSTEP - 2) {
      asm volatile("s_waitcnt vmcnt(4)" ::: "memory");
    } else {
      asm volatile("s_waitcnt vmcnt(0)" ::: "memory");
    }
    __builtin_amdgcn_s_barrier();
    asm volatile("" ::: "memory");
    COMPUTE2(s & 3);
  }

  // epilogue: bias + fp32 out
#pragma unroll
  for (int sn = 0; sn < 4; ++sn) {
    int gn = n0 + rn + sn * 16 + r15;
    float bv = bias[gn];
#pragma unroll
    for (int sm = 0; sm < 8; ++sm) {
      int gmBase = m0 + rm + sm * 16 + quad * 4;
#pragma unroll
      for (int r = 0; r < 4; ++r) {
        int gm = gmBase + r;
        if (gm < MROWS) out[(size_t)gm * CH + gn] = acc[sm][sn][r] + bv;
      }
    }
  }
}
#undef ISSUE2
#undef COMPUTE2

// ---- flash attention, NO-MAX softmax, base-2 domain, swapped QK^T (R6). ----
// R7: GEMM-style ASYNC staging. K and V^T tiles stored as [128 half-rows][32 elem]
// (hr = row*2 + half) -- byte-identical to the proven GEMM [128][32] layout with
// its XOR chunk swizzle. Staging = 4 global_load_lds per thread (linear LDS dest,
// per-lane pre-swizzled global source), double-buffered, ONE __syncthreads per
// tile: stage(t+1) issued right after the barrier, drained by the NEXT barrier
// -> full compute phase (32 MFMA + exp2) of slack. Removes per tile per wave:
// 4 ds_write_b128, 4 VGPR-roundtrip global loads, 1 barrier.
// OOB: K rows clamp to j=576 (their P forced 0); V chunk starts clamp to 576
// (reads [v576, pad0 x7], pad zeroed by pad_v; those j have P=0).
__global__ __launch_bounds__(256, 3)
void attn_kernel(const bf16* __restrict__ qrm, const bf16* __restrict__ krm,
                 const bf16* __restrict__ vt, bf16* __restrict__ ob) {
  __shared__ bf16 Ks[2][128 * 32];     // K tile [hr = j_loc*2+half][32], XOR-swizzled
  __shared__ bf16 Vt[2][128 * 32];     // V^T tile [hr = d*2+half][32], XOR-swizzled
  __shared__ bf16 Ps[4][2][16 * 72];   // per-wave, per-group private P [m][j] pad 72
  const int tid = threadIdx.x, lane = tid & 63, wid = tid >> 6;
  const int quad = lane >> 4, r15 = lane & 15;
  const int qt = blockIdx.x, bh = blockIdx.y;
  const int b_ = bh / NH, h = bh - b_ * NH;
  const bf16* vtb = vt + (size_t)bh * DHD * SEQP;
  const bf16* krmb = krm + (size_t)b_ * SEQ * CH + h * DHD;

  // Per-thread staging descriptors: slot q = wid*128 + c*64 + lane ->
  // hr = q>>2 in [0,128), physical chunk pp = q&3, logical chunk kc = pp^sw(hr).
  // Element offset within the 64-wide row: off = (hr&1)*32 + kc*8.
  int jloc_[2], off_[2];
  const bf16* vrow_[2];
#pragma unroll
  for (int c = 0; c < 2; ++c) {
    int q = wid * 128 + c * 64 + lane;
    int hr = q >> 2;
    int kc = (q & 3) ^ ((hr ^ (hr >> 2)) & 3);
    jloc_[c] = hr >> 1;                    // K: local j row; V: d row
    off_[c] = (hr & 1) * 32 + kc * 8;      // K: d offset;   V: local j offset
    vrow_[c] = vtb + (size_t)(hr >> 1) * SEQP;
  }

#define ASTAGE(J0, BUF)                                                        \
  {                                                                            \
    _Pragma("unroll") for (int c = 0; c < 2; ++c) {                            \
      int jr = (J0) + jloc_[c];                                                \
      if (jr > SEQ - 1) jr = SEQ - 1;                                          \
      async_ld16(krmb + (size_t)jr * CH + off_[c],                             \
                 &Ks[BUF][(wid * 128 + c * 64) * 8]);                          \
      int js = (J0) + off_[c];                                                 \
      if (js > SEQ - 1) js = SEQ - 1;                                          \
      async_ld16(vrow_[c] + js, &Vt[BUF][(wid * 128 + c * 64) * 8]);           \
    }                                                                          \
  }

  // Q fragments resident for both row groups (MFMA B operand: n=lane&15=q-row,
  // k=quad*8+j). q pre-scaled by 0.125*log2e.
  bf16x8 qf[2][2];
#pragma unroll
  for (int g = 0; g < 2; ++g) {
    int qrow = qt * 128 + wid * 32 + g * 16 + r15;
    if (qrow > SEQ - 1) qrow = SEQ - 1;
    const bf16* qp = qrm + (size_t)(b_ * SEQ + qrow) * CH + h * DHD + quad * 8;
    qf[g][0] = *(const bf16x8*)qp;
    qf[g][1] = *(const bf16x8*)(qp + 32);
  }

  f32x4 oacc[2][4];
#pragma unroll
  for (int g = 0; g < 2; ++g)
#pragma unroll
    for (int i = 0; i < 4; ++i) oacc[g][i] = (f32x4){0.f, 0.f, 0.f, 0.f};
  float lrow0 = 0.f, lrow1 = 0.f;  // per-lane partial row sum (row m = r15)

  bf16* P0 = &Ps[wid][0][0];
  bf16* P1 = &Ps[wid][1][0];

  ASTAGE(0, 0);
  int buf = 0;
  for (int t = 0; t < NJT; ++t) {
    const int j0 = t * 64;
    __syncthreads();  // drains stage(t) (issued one full tile ago) + buf reuse safe
    if (t + 1 < NJT) ASTAGE(j0 + 64, buf ^ 1);

    // S^T = K Q^T for BOTH groups in one pass over sj (K-frags read once).
    f32x4 s0[4], s1[4];
#pragma unroll
    for (int sj = 0; sj < 4; ++sj) {
      int hr0 = (sj * 16 + r15) * 2, hr1 = hr0 + 1;
      int p0c = quad ^ ((hr0 ^ (hr0 >> 2)) & 3);
      int p1c = quad ^ ((hr1 ^ (hr1 >> 2)) & 3);
      bf16x8 kf0 = *(const bf16x8*)(&Ks[buf][hr0 * 32 + p0c * 8]);
      bf16x8 kf1 = *(const bf16x8*)(&Ks[buf][hr1 * 32 + p1c * 8]);
      f32x4 z = (f32x4){0.f, 0.f, 0.f, 0.f};
      s0[sj] = MFMA_BF16(kf0, qf[0][0], z);
      s0[sj] = MFMA_BF16(kf1, qf[0][1], s0[sj]);
      s1[sj] = MFMA_BF16(kf0, qf[1][0], z);
      s1[sj] = MFMA_BF16(kf1, qf[1][1], s1[sj]);
    }

    // P = exp2(S) with OOB-j zeroed directly (j = j0 + sj*16 + quad*4 + r).
#pragma unroll
    for (int sj = 0; sj < 4; ++sj)
#pragma unroll
      for (int r = 0; r < 4; ++r) {
        int j = j0 + sj * 16 + quad * 4 + r;
        float e0 = (j <= SEQ - 1) ? __builtin_amdgcn_exp2f(s0[sj][r]) : 0.f;
        float e1 = (j <= SEQ - 1) ? __builtin_amdgcn_exp2f(s1[sj][r]) : 0.f;
        s0[sj][r] = e0; lrow0 += e0;
        s1[sj][r] = e1; lrow1 += e1;
      }

    // P store [m][j]: lane's 4 regs are contiguous in j -> packed b64 writes.
#pragma unroll
    for (int sj = 0; sj < 4; ++sj) {
      bf16x4 p0 = {(bf16)s0[sj][0], (bf16)s0[sj][1], (bf16)s0[sj][2], (bf16)s0[sj][3]};
      bf16x4 p1 = {(bf16)s1[sj][0], (bf16)s1[sj][1], (bf16)s1[sj][2], (bf16)s1[sj][3]};
      *(bf16x4*)(P0 + r15 * 72 + sj * 16 + quad * 4) = p0;
      *(bf16x4*)(P1 + r15 * 72 + sj * 16 + quad * 4) = p1;
    }
    asm volatile("s_waitcnt lgkmcnt(0)" ::: "memory");  // wave-private RAW

    // O += P V ; V-frags read ONCE, shared by both groups.
#pragma unroll
    for (int kc = 0; kc < 2; ++kc) {
      bf16x8 pf0 = *(const bf16x8*)(P0 + r15 * 72 + kc * 32 + quad * 8);
      bf16x8 pf1 = *(const bf16x8*)(P1 + r15 * 72 + kc * 32 + quad * 8);
#pragma unroll
      for (int sd = 0; sd < 4; ++sd) {
        int hrv = (sd * 16 + r15) * 2 + kc;
        int pv = quad ^ ((hrv ^ (hrv >> 2)) & 3);
        bf16x8 vf = *(const bf16x8*)(&Vt[buf][hrv * 32 + pv * 8]);
        oacc[0][sd] = MFMA_BF16(pf0, vf, oacc[0][sd]);
        oacc[1][sd] = MFMA_BF16(pf1, vf, oacc[1][sd]);
      }
    }
    buf ^= 1;
  }
#undef ASTAGE

  // Row sums: reduce across the 4 lanes sharing r15 (quads) -> full sum at every lane.
  lrow0 += __shfl_xor(lrow0, 16);
  lrow0 += __shfl_xor(lrow0, 32);
  lrow1 += __shfl_xor(lrow1, 16);
  lrow1 += __shfl_xor(lrow1, 32);

  // write O -> attn_out [b*577+n][h*64+d]; O C/D layout: row m=quad*4+r, col d=sd*16+r15.
  // Row sum for m lives at lanes with r15==m -> fetch via one shuffle (src lane = m).
#pragma unroll
  for (int g = 0; g < 2; ++g) {
    float lr = (g == 0) ? lrow0 : lrow1;
#pragma unroll
    for (int r = 0; r < 4; ++r) {
      int m = quad * 4 + r;
      float rs = __shfl(lr, m);
      int orow = qt * 128 + wid * 32 + g * 16 + m;
      if (orow < SEQ) {
        float inv = 1.0f / rs;
        size_t rowoff = ((size_t)(b_ * SEQ + orow)) * CH + h * DHD;
#pragma unroll
        for (int sd = 0; sd < 4; ++sd)
          ob[rowoff + sd * 16 + r15] = (bf16)(oacc[g][sd][r] * inv);
      }
    }
  }
}

extern "C" void kernel_launch(void* const* d_in, const int* in_sizes, int n_in,
                              void* d_out, int out_size, void* d_ws, size_t ws_size,
                              hipStream_t stream) {
  const float* x      = (const float*)d_in[0];
  const float* qkv_w  = (const float*)d_in[1];
  const float* qkv_b  = (const float*)d_in[2];
  const float* proj_w = (const float*)d_in[3];
  const float* proj_b = (const float*)d_in[4];
  float* out = (float*)d_out;

  char* w = (char*)d_ws;
  // workspace layout (bytes), total 117,325,824:
  bf16* xb  = (bf16*)(w);               // [18464,768] x_bf16, reused as attn_out
  bf16* wqp = (bf16*)(w + 28360704);    // qkv_w bf16; later aliased by proj_w bf16
  bf16* qrm = (bf16*)(w + 31899648);    // [18464,768] scaled Q
  bf16* krm = (bf16*)(w + 60260352);    // [18464,768] K
  bf16* vtb = (bf16*)(w + 88621056);    // [32,12,64,584] V^T
  // GEMM m-tail reads spill into the wqp region: finite, discarded.

  cvt_bf16<<<(MROWS * CH / 4 + 255) / 256, 256, 0, stream>>>(x, xb, MROWS * CH);
  cvt_bf16<<<(NQKV * CH / 4 + 255) / 256, 256, 0, stream>>>(qkv_w, wqp, NQKV * CH);
  pad_v<<<(BB * NH * DHD + 255) / 256, 256, 0, stream>>>(vtb);

  gemm_qkv<<<dim3(NQKV / 128, 145), 256, 0, stream>>>(
      xb, wqp, qkv_b, qrm, krm, vtb);

  attn_kernel<<<dim3(5, BB * NH), 256, 0, stream>>>(qrm, krm, vtb, xb);

  // proj weights convert AFTER attention (stream-ordered) so it can alias wqp
  cvt_bf16<<<(CH * CH / 4 + 255) / 256, 256, 0, stream>>>(proj_w, wqp, CH * CH);

  gemm_proj<<<dim3(CH / 256, 73), 512, 0, stream>>>(xb, wqp, proj_b, out);
}

// Round 8
// 340.511 us; speedup vs baseline: 1.5015x; 1.0286x over previous
//
#include <hip/hip_runtime.h>

typedef __bf16 bf16;
typedef __attribute__((ext_vector_type(4))) __bf16 bf16x4;
typedef __attribute__((ext_vector_type(8))) __bf16 bf16x8;
typedef __attribute__((ext_vector_type(4))) float f32x4;

#define MFMA_BF16(A_, B_, C_) __builtin_amdgcn_mfma_f32_16x16x32_bf16(A_, B_, C_, 0, 0, 0)

// Problem dims
#define BB    32
#define SEQ   577
#define CH    768
#define NH    12
#define DHD   64
#define MROWS (BB * SEQ)   // 18464
#define NQKV  2304
#define SEQP  584          // V^T row stride (73*8)
// q scale folded with log2(e): softmax computed in base-2 domain
#define QSCALE 0.1803368801111204f

#define NSTEP 24           // K-steps of 32 for the 256^2 proj GEMM (768 = 24*32)
#define NJT   10           // attn j-tiles (577 = 9*64 + 1)

// ---- bijective XCD-chunked remap (m204): hw linear id -> work id such that
// each XCD's round-robin share (ids with equal id&7) is a CONTIGUOUS work range.
__device__ __forceinline__ int xcd_chunk(int bid, int nwg) {
  int q8 = nwg >> 3, r8 = nwg & 7;
  int xcd = bid & 7, sub = bid >> 3;
  return (xcd < r8 ? xcd * (q8 + 1) : r8 * (q8 + 1) + (xcd - r8) * q8) + sub;
}

// ---- async global->LDS 16B (wave-uniform LDS base + lane*16, per guide §5) ----
__device__ __forceinline__ void async_ld16(const bf16* g, bf16* l) {
  __builtin_amdgcn_global_load_lds(
      (const __attribute__((address_space(1))) void*)g,
      (__attribute__((address_space(3))) void*)l, 16, 0, 0);
}

// ---- fp32 -> bf16 convert ----
__global__ __launch_bounds__(256) void cvt_bf16(const float* __restrict__ src,
                                                bf16* __restrict__ dst, int n) {
  int idx = (blockIdx.x * 256 + threadIdx.x) * 4;
  if (idx >= n) return;
  float4 v = *(const float4*)(src + idx);
  bf16x4 o = {(bf16)v.x, (bf16)v.y, (bf16)v.z, (bf16)v.w};
  *(bf16x4*)(dst + idx) = o;
}

// ---- zero the 7-element pad of each V^T row (j in [577,584)) so attention's
// staged V reads at clamped chunk start 576 see zeros beyond j=576.
__global__ __launch_bounds__(256) void pad_v(bf16* __restrict__ vt) {
  int r = blockIdx.x * 256 + threadIdx.x;
  if (r < BB * NH * DHD) {
    bf16* p = vt + (size_t)r * SEQP + SEQ;
#pragma unroll
    for (int i = 0; i < 7; ++i) p[i] = (bf16)0.f;
  }
}

// ---- 128x128x(K=768) bf16 MFMA GEMM (qkv), R0-proven structure (145us) ----
// Double-buffered single-barrier K-loop: loads for step k+1 issued right after the
// barrier, drained by the NEXT barrier -> each drain has a full compute phase of slack.
// R8: XCD-chunked block swizzle ONLY (launch bounds untouched -- R2's regression
// bundled this with a 5-block occupancy change; FETCH dropped 133->94MB there, so
// the swizzle itself is locality-positive). Consecutive work ids (n-fast within an
// m-row) now land on ONE XCD -> A m-panel + W stay in that XCD's L2.
// qkv epilogue: q -> qrm [M,768] (scaled), k -> krm [M,768], v -> vt [B,H,64,SEQP]
__global__ __launch_bounds__(256, 2)
void gemm_qkv(const bf16* __restrict__ A, const bf16* __restrict__ W,
              const float* __restrict__ bias,
              bf16* __restrict__ qrm, bf16* __restrict__ krm, bf16* __restrict__ vt) {
  __shared__ bf16 As[2][128 * 32];
  __shared__ bf16 Bs[2][128 * 32];
  const int tid = threadIdx.x, lane = tid & 63, wid = tid >> 6;
  const int quad = lane >> 4, r15 = lane & 15;
  const int nbx = (int)gridDim.x;
  const int wg = xcd_chunk((int)blockIdx.y * nbx + (int)blockIdx.x,
                           nbx * (int)gridDim.y);
  const int m0 = (wg / nbx) * 128, n0 = (wg % nbx) * 128;
  const int waveM = wid & 1, waveN = wid >> 1;

  // staging: 512 16B chunks per tile; XOR chunk swizzle -> fragment ds_read_b128 2-way (free)
  const bf16* aSrc[2];
  const bf16* bSrc[2];
  for (int c = 0; c < 2; ++c) {
    int q = wid * 128 + c * 64 + lane;
    int row = q >> 2;
    int sw = (row ^ (row >> 2)) & 3;
    int kc = (q & 3) ^ sw;
    aSrc[c] = A + (size_t)(m0 + row) * CH + kc * 8;
    bSrc[c] = W + (size_t)(n0 + row) * CH + kc * 8;
  }

  f32x4 acc[4][4];
#pragma unroll
  for (int i = 0; i < 4; ++i)
#pragma unroll
    for (int j = 0; j < 4; ++j) acc[i][j] = (f32x4){0.f, 0.f, 0.f, 0.f};

#define GSTAGE(K0, BUF)                                                   \
  {                                                                       \
    _Pragma("unroll") for (int c = 0; c < 2; ++c) {                       \
      async_ld16(aSrc[c] + (K0), &As[BUF][(wid * 128 + c * 64) * 8]);     \
      async_ld16(bSrc[c] + (K0), &Bs[BUF][(wid * 128 + c * 64) * 8]);     \
    }                                                                     \
  }

#define GCOMPUTE(BUF)                                                     \
  {                                                                       \
    bf16x8 af[4], bfr[4];                                                 \
    _Pragma("unroll") for (int s = 0; s < 4; ++s) {                       \
      int rowA = waveM * 64 + s * 16 + r15;                               \
      int ca = quad ^ ((rowA ^ (rowA >> 2)) & 3);                         \
      af[s] = *(const bf16x8*)(&As[BUF][rowA * 32 + ca * 8]);             \
      int rowB = waveN * 64 + s * 16 + r15;                               \
      int cb = quad ^ ((rowB ^ (rowB >> 2)) & 3);                         \
      bfr[s] = *(const bf16x8*)(&Bs[BUF][rowB * 32 + cb * 8]);            \
    }                                                                     \
    _Pragma("unroll") for (int sm = 0; sm < 4; ++sm)                      \
      _Pragma("unroll") for (int sn = 0; sn < 4; ++sn)                    \
        acc[sm][sn] = MFMA_BF16(af[sm], bfr[sn], acc[sm][sn]);            \
  }

  GSTAGE(0, 0);
  for (int k0 = 0; k0 < CH; k0 += 64) {
    __syncthreads();                       // drains buf0 loads (issued prev iter / prologue)
    GSTAGE(k0 + 32, 1);                    // overlaps compute on buf0
    GCOMPUTE(0);
    __syncthreads();                       // drains buf1 loads; all waves done with buf0
    if (k0 + 64 < CH) GSTAGE(k0 + 64, 0);  // overlaps compute on buf1
    GCOMPUTE(1);
  }

  // epilogue: C/D layout row=(lane>>4)*4+reg, col=lane&15 (verified m89/m91)
  int t = (n0 >= 1536) ? 2 : (n0 >= 768 ? 1 : 0);  // 128-tiles never straddle 768
#pragma unroll
  for (int sn = 0; sn < 4; ++sn) {
    int gn = n0 + waveN * 64 + sn * 16 + r15;
    float bv = bias[gn];
    int col = gn - t * CH;  // [0,768)
    int h = col >> 6, d = col & 63;
#pragma unroll
    for (int sm = 0; sm < 4; ++sm) {
      int gmBase = m0 + waveM * 64 + sm * 16 + quad * 4;
#pragma unroll
      for (int r = 0; r < 4; ++r) {
        int gm = gmBase + r;
        if (gm < MROWS) {
          float v = acc[sm][sn][r] + bv;
          if (t == 0) {
            qrm[(size_t)gm * CH + col] = (bf16)(v * QSCALE);
          } else if (t == 1) {
            krm[(size_t)gm * CH + col] = (bf16)v;
          } else {
            int b_ = gm / SEQ;
            int n_ = gm - b_ * SEQ;
            vt[((size_t)(b_ * NH + h) * DHD + d) * SEQP + n_] = (bf16)v;
          }
        }
      }
    }
  }
}
#undef GSTAGE
#undef GCOMPUTE

// ---- 256x256x(K=768) proj GEMM, R3-proven (single 219-block round). ----
// Counted-vmcnt pipeline, 4 LDS buffers, prefetch distance 2, one raw s_barrier
// per 32-K step.
__global__ __launch_bounds__(512, 2)
void gemm_proj(const bf16* __restrict__ A, const bf16* __restrict__ W,
               const float* __restrict__ bias, float* __restrict__ out) {
  __shared__ bf16 As[4][256 * 32];  // [buf][row*32 + chunk2*8], 16 KiB each
  __shared__ bf16 Bs[4][256 * 32];
  const int tid = threadIdx.x, lane = tid & 63, wid = tid >> 6;
  const int quad = lane >> 4, r15 = lane & 15;

  const int nbx = (int)gridDim.x;
  const int wg = xcd_chunk((int)blockIdx.y * nbx + (int)blockIdx.x,
                           nbx * (int)gridDim.y);
  const int m0 = (wg / nbx) * 256, n0 = (wg % nbx) * 256;

  const int rm = (wid >> 2) * 128;  // wave row base (2 waves in M)
  const int rn = (wid & 3) * 64;    // wave col base (4 waves in N)

  int aOff[2], bOff[2];
#pragma unroll
  for (int i = 0; i < 2; ++i) {
    int slot = i * 512 + tid;
    int row = slot >> 2, pc2 = slot & 3;
    int gc2 = pc2 ^ ((row ^ (row >> 2)) & 3);
    aOff[i] = (m0 + row) * CH + gc2 * 8;
    bOff[i] = (n0 + row) * CH + gc2 * 8;
  }

  f32x4 acc[8][4];
#pragma unroll
  for (int i = 0; i < 8; ++i)
#pragma unroll
    for (int j = 0; j < 4; ++j) acc[i][j] = (f32x4){0.f, 0.f, 0.f, 0.f};

#define ISSUE2(S)                                                              \
  {                                                                            \
    const int kb_ = (S) * 32;                                                  \
    const int bf_ = (S) & 3;                                                   \
    _Pragma("unroll") for (int i = 0; i < 2; ++i) {                            \
      async_ld16(A + aOff[i] + kb_, &As[bf_][(i * 512 + tid) * 8]);            \
      async_ld16(W + bOff[i] + kb_, &Bs[bf_][(i * 512 + tid) * 8]);            \
    }                                                                          \
  }

#define COMPUTE2(BF)                                                           \
  {                                                                            \
    bf16x8 bfr[4], afr[8];                                                     \
    _Pragma("unroll") for (int sn = 0; sn < 4; ++sn) {                         \
      int fr = rn + sn * 16 + r15;                                             \
      int pc2 = quad ^ ((fr ^ (fr >> 2)) & 3);                                 \
      bfr[sn] = *(const bf16x8*)(&Bs[BF][fr * 32 + pc2 * 8]);                  \
    }                                                                          \
    _Pragma("unroll") for (int sm = 0; sm < 8; ++sm) {                         \
      int fr = rm + sm * 16 + r15;                                             \
      int pc2 = quad ^ ((fr ^ (fr >> 2)) & 3);                                 \
      afr[sm] = *(const bf16x8*)(&As[BF][fr * 32 + pc2 * 8]);                  \
    }                                                                          \
    _Pragma("unroll") for (int sm = 0; sm < 8; ++sm)                           \
      _Pragma("unroll") for (int sn = 0; sn < 4; ++sn)                         \
        acc[sm][sn] = MFMA_BF16(afr[sm], bfr[sn], acc[sm][sn]);                \
  }

  ISSUE2(0);
  ISSUE2(1);
  for (int s = 0; s < NSTEP; ++s) {
    if (s < NSTEP - 2) {
      ISSUE2(s + 2);
      asm volatile("s_waitcnt vmcnt(8)" ::: "memory");
    } else if (s == NSTEP - 2) {
      asm volatile("s_waitcnt vmcnt(4)" ::: "memory");
    } else {
      asm volatile("s_waitcnt vmcnt(0)" ::: "memory");
    }
    __builtin_amdgcn_s_barrier();
    asm volatile("" ::: "memory");
    COMPUTE2(s & 3);
  }

  // epilogue: bias + fp32 out
#pragma unroll
  for (int sn = 0; sn < 4; ++sn) {
    int gn = n0 + rn + sn * 16 + r15;
    float bv = bias[gn];
#pragma unroll
    for (int sm = 0; sm < 8; ++sm) {
      int gmBase = m0 + rm + sm * 16 + quad * 4;
#pragma unroll
      for (int r = 0; r < 4; ++r) {
        int gm = gmBase + r;
        if (gm < MROWS) out[(size_t)gm * CH + gn] = acc[sm][sn][r] + bv;
      }
    }
  }
}
#undef ISSUE2
#undef COMPUTE2

// ---- flash attention, NO-MAX softmax, base-2 domain, swapped QK^T (R6),
// GEMM-style async double-buffered staging (R7). ----
// R8: XCD-chunked block swizzle. Work id = bh*5 + qt, so the 5 q-tile blocks of
// each (b,h) -- which REUSE the same 147KB K/V -- land on ONE XCD. Previously
// they round-robined across all 8 XCDs, so each XCD's private L2 fetched its own
// K/V copy (R4 measured the resulting ~3x over-fetch) and every stage drain ran
// at HBM latency. Now K/V is fetched into one L2 and 4/5 blocks hit L2-local.
__global__ __launch_bounds__(256, 3)
void attn_kernel(const bf16* __restrict__ qrm, const bf16* __restrict__ krm,
                 const bf16* __restrict__ vt, bf16* __restrict__ ob) {
  __shared__ bf16 Ks[2][128 * 32];     // K tile [hr = j_loc*2+half][32], XOR-swizzled
  __shared__ bf16 Vt[2][128 * 32];     // V^T tile [hr = d*2+half][32], XOR-swizzled
  __shared__ bf16 Ps[4][2][16 * 72];   // per-wave, per-group private P [m][j] pad 72
  const int tid = threadIdx.x, lane = tid & 63, wid = tid >> 6;
  const int quad = lane >> 4, r15 = lane & 15;
  const int nbx = (int)gridDim.x;  // 5
  const int wg = xcd_chunk((int)blockIdx.y * nbx + (int)blockIdx.x,
                           nbx * (int)gridDim.y);
  const int qt = wg % nbx, bh = wg / nbx;
  const int b_ = bh / NH, h = bh - b_ * NH;
  const bf16* vtb = vt + (size_t)bh * DHD * SEQP;
  const bf16* krmb = krm + (size_t)b_ * SEQ * CH + h * DHD;

  // Per-thread staging descriptors: slot q = wid*128 + c*64 + lane ->
  // hr = q>>2 in [0,128), physical chunk pp = q&3, logical chunk kc = pp^sw(hr).
  // Element offset within the 64-wide row: off = (hr&1)*32 + kc*8.
  int jloc_[2], off_[2];
  const bf16* vrow_[2];
#pragma unroll
  for (int c = 0; c < 2; ++c) {
    int q = wid * 128 + c * 64 + lane;
    int hr = q >> 2;
    int kc = (q & 3) ^ ((hr ^ (hr >> 2)) & 3);
    jloc_[c] = hr >> 1;                    // K: local j row; V: d row
    off_[c] = (hr & 1) * 32 + kc * 8;      // K: d offset;   V: local j offset
    vrow_[c] = vtb + (size_t)(hr >> 1) * SEQP;
  }

#define ASTAGE(J0, BUF)                                                        \
  {                                                                            \
    _Pragma("unroll") for (int c = 0; c < 2; ++c) {                            \
      int jr = (J0) + jloc_[c];                                                \
      if (jr > SEQ - 1) jr = SEQ - 1;                                          \
      async_ld16(krmb + (size_t)jr * CH + off_[c],                             \
                 &Ks[BUF][(wid * 128 + c * 64) * 8]);                          \
      int js = (J0) + off_[c];                                                 \
      if (js > SEQ - 1) js = SEQ - 1;                                          \
      async_ld16(vrow_[c] + js, &Vt[BUF][(wid * 128 + c * 64) * 8]);           \
    }                                                                          \
  }

  // Q fragments resident for both row groups (MFMA B operand: n=lane&15=q-row,
  // k=quad*8+j). q pre-scaled by 0.125*log2e.
  bf16x8 qf[2][2];
#pragma unroll
  for (int g = 0; g < 2; ++g) {
    int qrow = qt * 128 + wid * 32 + g * 16 + r15;
    if (qrow > SEQ - 1) qrow = SEQ - 1;
    const bf16* qp = qrm + (size_t)(b_ * SEQ + qrow) * CH + h * DHD + quad * 8;
    qf[g][0] = *(const bf16x8*)qp;
    qf[g][1] = *(const bf16x8*)(qp + 32);
  }

  f32x4 oacc[2][4];
#pragma unroll
  for (int g = 0; g < 2; ++g)
#pragma unroll
    for (int i = 0; i < 4; ++i) oacc[g][i] = (f32x4){0.f, 0.f, 0.f, 0.f};
  float lrow0 = 0.f, lrow1 = 0.f;  // per-lane partial row sum (row m = r15)

  bf16* P0 = &Ps[wid][0][0];
  bf16* P1 = &Ps[wid][1][0];

  ASTAGE(0, 0);
  int buf = 0;
  for (int t = 0; t < NJT; ++t) {
    const int j0 = t * 64;
    __syncthreads();  // drains stage(t) (issued one full tile ago) + buf reuse safe
    if (t + 1 < NJT) ASTAGE(j0 + 64, buf ^ 1);

    // S^T = K Q^T for BOTH groups in one pass over sj (K-frags read once).
    f32x4 s0[4], s1[4];
#pragma unroll
    for (int sj = 0; sj < 4; ++sj) {
      int hr0 = (sj * 16 + r15) * 2, hr1 = hr0 + 1;
      int p0c = quad ^ ((hr0 ^ (hr0 >> 2)) & 3);
      int p1c = quad ^ ((hr1 ^ (hr1 >> 2)) & 3);
      bf16x8 kf0 = *(const bf16x8*)(&Ks[buf][hr0 * 32 + p0c * 8]);
      bf16x8 kf1 = *(const bf16x8*)(&Ks[buf][hr1 * 32 + p1c * 8]);
      f32x4 z = (f32x4){0.f, 0.f, 0.f, 0.f};
      s0[sj] = MFMA_BF16(kf0, qf[0][0], z);
      s0[sj] = MFMA_BF16(kf1, qf[0][1], s0[sj]);
      s1[sj] = MFMA_BF16(kf0, qf[1][0], z);
      s1[sj] = MFMA_BF16(kf1, qf[1][1], s1[sj]);
    }

    // P = exp2(S) with OOB-j zeroed directly (j = j0 + sj*16 + quad*4 + r).
#pragma unroll
    for (int sj = 0; sj < 4; ++sj)
#pragma unroll
      for (int r = 0; r < 4; ++r) {
        int j = j0 + sj * 16 + quad * 4 + r;
        float e0 = (j <= SEQ - 1) ? __builtin_amdgcn_exp2f(s0[sj][r]) : 0.f;
        float e1 = (j <= SEQ - 1) ? __builtin_amdgcn_exp2f(s1[sj][r]) : 0.f;
        s0[sj][r] = e0; lrow0 += e0;
        s1[sj][r] = e1; lrow1 += e1;
      }

    // P store [m][j]: lane's 4 regs are contiguous in j -> packed b64 writes.
#pragma unroll
    for (int sj = 0; sj < 4; ++sj) {
      bf16x4 p0 = {(bf16)s0[sj][0], (bf16)s0[sj][1], (bf16)s0[sj][2], (bf16)s0[sj][3]};
      bf16x4 p1 = {(bf16)s1[sj][0], (bf16)s1[sj][1], (bf16)s1[sj][2], (bf16)s1[sj][3]};
      *(bf16x4*)(P0 + r15 * 72 + sj * 16 + quad * 4) = p0;
      *(bf16x4*)(P1 + r15 * 72 + sj * 16 + quad * 4) = p1;
    }
    asm volatile("s_waitcnt lgkmcnt(0)" ::: "memory");  // wave-private RAW

    // O += P V ; V-frags read ONCE, shared by both groups.
#pragma unroll
    for (int kc = 0; kc < 2; ++kc) {
      bf16x8 pf0 = *(const bf16x8*)(P0 + r15 * 72 + kc * 32 + quad * 8);
      bf16x8 pf1 = *(const bf16x8*)(P1 + r15 * 72 + kc * 32 + quad * 8);
#pragma unroll
      for (int sd = 0; sd < 4; ++sd) {
        int hrv = (sd * 16 + r15) * 2 + kc;
        int pv = quad ^ ((hrv ^ (hrv >> 2)) & 3);
        bf16x8 vf = *(const bf16x8*)(&Vt[buf][hrv * 32 + pv * 8]);
        oacc[0][sd] = MFMA_BF16(pf0, vf, oacc[0][sd]);
        oacc[1][sd] = MFMA_BF16(pf1, vf, oacc[1][sd]);
      }
    }
    buf ^= 1;
  }
#undef ASTAGE

  // Row sums: reduce across the 4 lanes sharing r15 (quads) -> full sum at every lane.
  lrow0 += __shfl_xor(lrow0, 16);
  lrow0 += __shfl_xor(lrow0, 32);
  lrow1 += __shfl_xor(lrow1, 16);
  lrow1 += __shfl_xor(lrow1, 32);

  // write O -> attn_out [b*577+n][h*64+d]; O C/D layout: row m=quad*4+r, col d=sd*16+r15.
  // Row sum for m lives at lanes with r15==m -> fetch via one shuffle (src lane = m).
#pragma unroll
  for (int g = 0; g < 2; ++g) {
    float lr = (g == 0) ? lrow0 : lrow1;
#pragma unroll
    for (int r = 0; r < 4; ++r) {
      int m = quad * 4 + r;
      float rs = __shfl(lr, m);
      int orow = qt * 128 + wid * 32 + g * 16 + m;
      if (orow < SEQ) {
        float inv = 1.0f / rs;
        size_t rowoff = ((size_t)(b_ * SEQ + orow)) * CH + h * DHD;
#pragma unroll
        for (int sd = 0; sd < 4; ++sd)
          ob[rowoff + sd * 16 + r15] = (bf16)(oacc[g][sd][r] * inv);
      }
    }
  }
}

extern "C" void kernel_launch(void* const* d_in, const int* in_sizes, int n_in,
                              void* d_out, int out_size, void* d_ws, size_t ws_size,
                              hipStream_t stream) {
  const float* x      = (const float*)d_in[0];
  const float* qkv_w  = (const float*)d_in[1];
  const float* qkv_b  = (const float*)d_in[2];
  const float* proj_w = (const float*)d_in[3];
  const float* proj_b = (const float*)d_in[4];
  float* out = (float*)d_out;

  char* w = (char*)d_ws;
  // workspace layout (bytes), total 117,325,824:
  bf16* xb  = (bf16*)(w);               // [18464,768] x_bf16, reused as attn_out
  bf16* wqp = (bf16*)(w + 28360704);    // qkv_w bf16; later aliased by proj_w bf16
  bf16* qrm = (bf16*)(w + 31899648);    // [18464,768] scaled Q
  bf16* krm = (bf16*)(w + 60260352);    // [18464,768] K
  bf16* vtb = (bf16*)(w + 88621056);    // [32,12,64,584] V^T
  // GEMM m-tail reads spill into the wqp region: finite, discarded.

  cvt_bf16<<<(MROWS * CH / 4 + 255) / 256, 256, 0, stream>>>(x, xb, MROWS * CH);
  cvt_bf16<<<(NQKV * CH / 4 + 255) / 256, 256, 0, stream>>>(qkv_w, wqp, NQKV * CH);
  pad_v<<<(BB * NH * DHD + 255) / 256, 256, 0, stream>>>(vtb);

  gemm_qkv<<<dim3(NQKV / 128, 145), 256, 0, stream>>>(
      xb, wqp, qkv_b, qrm, krm, vtb);

  attn_kernel<<<dim3(5, BB * NH), 256, 0, stream>>>(qrm, krm, vtb, xb);

  // proj weights convert AFTER attention (stream-ordered) so it can alias wqp
  cvt_bf16<<<(CH * CH / 4 + 255) / 256, 256, 0, stream>>>(proj_w, wqp, CH * CH);

  gemm_proj<<<dim3(CH / 256, 73), 512, 0, stream>>>(xb, wqp, proj_b, out);
}